// Round 10
// baseline (7664.281 us; speedup 1.0000x reference)
//
#include <hip/hip_runtime.h>

typedef __bf16 bf16x8 __attribute__((ext_vector_type(8)));
typedef float  f32x16 __attribute__((ext_vector_type(16)));

#define NROWS 8192
#define DK    4096
#define MCOLS 4096
#define NKT   64            // K-tiles of BK=64
#define IMG   16384         // bf16 elems per 256x64 tile image (32 KB)
#define X_TILES 32
#define W_TILES 16

#define X_ELEMS ((size_t)NROWS * DK)
#define A_ELEMS ((size_t)MCOLS * DK)
#define WS_NEED ((X_ELEMS + A_ELEMS) * 2)

#define BAR()  do { __builtin_amdgcn_s_barrier(); asm volatile("" ::: "memory"); } while (0)
#define VM0    asm volatile("s_waitcnt vmcnt(0)" ::: "memory")

__device__ __forceinline__ bf16x8 pack8(const float4& a, const float4& b) {
  bf16x8 r;
  r[0] = (__bf16)a.x; r[1] = (__bf16)a.y; r[2] = (__bf16)a.z; r[3] = (__bf16)a.w;
  r[4] = (__bf16)b.x; r[5] = (__bf16)b.y; r[6] = (__bf16)b.z; r[7] = (__bf16)b.w;
  return r;
}

__device__ __forceinline__ void gload16(const __bf16* g, __bf16* l) {
  __builtin_amdgcn_global_load_lds(
      (const __attribute__((address_space(1))) void*)g,
      (__attribute__((address_space(3))) void*)l, 16, 0, 0);
}

// 32x32-fragment-major image: [tile][kt][frag32 0..7][ks 0..3][lane 0..63][8]
// element (lane, j) = src[tile*256 + frag32*32 + (lane&31)][kt*64 + ks*16 + (lane>>5)*8 + j]
__global__ __launch_bounds__(256) void conv32(const float* __restrict__ src,
                                              __bf16* __restrict__ dst,
                                              int ntiles) {
  const int total = ntiles * NKT * 2048;
  for (int i = blockIdx.x * blockDim.x + threadIdx.x; i < total;
       i += gridDim.x * blockDim.x) {
    int lane = i & 63;
    int ks   = (i >> 6) & 3;
    int mf   = (i >> 8) & 7;
    int kt   = (i >> 11) & 63;
    int tm   = i >> 17;
    int row = tm * 256 + mf * 32 + (lane & 31);
    int k   = kt * 64 + ks * 16 + (lane >> 5) * 8;
    const float4* p = (const float4*)(src + (size_t)row * DK + k);
    float4 a = p[0], b = p[1];
    *(bf16x8*)(dst + (size_t)i * 8) = pack8(a, b);
  }
}

// ---- 32x32 MFMA, X-in-regs, W 2-slot LDS dbuf (2 blocks/CU), 1 VM0+BAR/tile
__global__ __launch_bounds__(512, 4) void gemm13(const __bf16* __restrict__ wsX,
                                                 const __bf16* __restrict__ wsW,
                                                 float* __restrict__ out) {
  __shared__ __align__(16) __bf16 Wls[2 * IMG];   // 64 KB -> 2 blocks/CU
  __shared__ float rowsum[2][256];

  const int t    = threadIdx.x;
  const int lane = t & 63;
  const int w    = t >> 6;           // 0..7
  const int wr4  = w >> 1;           // 0..3 : rows wr4*64..+63
  const int wc2  = w & 1;            // 0..1 : cols wc2*128..+127
  const int hi   = lane >> 5;        // 0..1

  unsigned bid = blockIdx.x;
  unsigned xcd = bid & 7, seq = bid >> 3;
  const int tile_m = (int)((xcd >> 1) * 8 + (seq & 7));    // 0..31
  const int tile_n = (int)((xcd & 1) * 8 + (seq >> 3));    // 0..15

  const __bf16* xbase = wsX + (size_t)tile_m * ((size_t)NKT * IMG);
  const __bf16* wbase = wsW + (size_t)tile_n * ((size_t)NKT * IMG);
  const __bf16* xw = xbase + ((size_t)(wr4 * 2) * 4) * 512 + (size_t)lane * 8;

  f32x16 acc[2][4] = {};               // [mt][nf] : 128 VGPR
  bf16x8 xa[2][4], xb[2][4];           // [mt][ks]
  bf16x8 b[4][2];                      // [nf][ks-half]

  auto loadX = [&](bf16x8 (&x)[2][4], int h) {       // 8 plain global b128
    const __bf16* p = xw + (size_t)h * IMG;
#pragma unroll
    for (int mt = 0; mt < 2; ++mt)
#pragma unroll
      for (int ks = 0; ks < 4; ++ks)
        x[mt][ks] = *(const bf16x8*)(p + (mt * 4 + ks) * 512);
  };

  auto readB = [&](const __bf16* slot, int kh) {     // 8 ds_read_b128
#pragma unroll
    for (int nf = 0; nf < 4; ++nf)
#pragma unroll
      for (int ks = 0; ks < 2; ++ks)
        b[nf][ks] = *(const bf16x8*)(slot + ((wc2 * 4 + nf) * 4 + kh * 2 + ks) * 512
                                     + lane * 8);
  };

  auto stageW = [&](const __bf16* src, __bf16* dst) {  // 8192 elems, 2 gloads
    const __bf16* s0 = src + t * 8;
    __bf16* d0 = dst + w * 512;
    gload16(s0, d0);
    gload16(s0 + 4096, d0 + 4096);
  };

  auto group = [&](const bf16x8 (&x)[2][4], int kh) { // 16 MFMA
    __builtin_amdgcn_s_setprio(1);
#pragma unroll
    for (int ks = 0; ks < 2; ++ks)
#pragma unroll
      for (int mt = 0; mt < 2; ++mt)
#pragma unroll
        for (int nf = 0; nf < 4; ++nf)
          acc[mt][nf] = __builtin_amdgcn_mfma_f32_32x32x16_bf16(
              x[mt][kh * 2 + ks], b[nf][ks], acc[mt][nf], 0, 0, 0);
    __builtin_amdgcn_s_setprio(0);
  };

  auto tile = [&](int h, bf16x8 (&xcur)[2][4], bf16x8 (&xnext)[2][4]) {
    const __bf16* slotR = Wls + (h & 1) * IMG;
    __bf16* slotS = Wls + ((h + 1) & 1) * IMG;

    if (h + 1 < NKT) loadX(xnext, h + 1);          // X(h+1): max landing time
    readB(slotR, 0);                               // b ks0,1 of W(h)
    if (h + 1 < NKT) {                             // stage W(h+1) -> other slot
      const __bf16* wsrc = wbase + (size_t)(h + 1) * IMG;
      stageW(wsrc, slotS);
      stageW(wsrc + 8192, slotS + 8192);
    }
    group(xcur, 0);
    readB(slotR, 1);                               // b ks2,3
    group(xcur, 1);
    VM0;                                           // all X + W gloads landed
    BAR();                                         // slotS ready, slotR reads done
  };

  // prologue: W(0)->slot0, X(0)->xa
  stageW(wbase,        Wls);
  stageW(wbase + 8192, Wls + 8192);
  loadX(xa, 0);
  VM0;
  BAR();

  for (int h = 0; h < NKT; h += 2) {
    tile(h,     xa, xb);
    tile(h + 1, xb, xa);
  }

  // ---- epilogue: row sums of squares ----
  // acc[mt][nf] reg r: row = tile_m*256 + (wr4*2+mt)*32 + (r&3) + 8*(r>>2) + 4*hi
  float v[2][16];
#pragma unroll
  for (int mt = 0; mt < 2; ++mt)
#pragma unroll
    for (int r = 0; r < 16; ++r) {
      float s = 0.f;
#pragma unroll
      for (int nf = 0; nf < 4; ++nf) {
        float c = acc[mt][nf][r];
        s += c * c;
      }
      s += __shfl_xor(s, 1, 64);
      s += __shfl_xor(s, 2, 64);
      s += __shfl_xor(s, 4, 64);
      s += __shfl_xor(s, 8, 64);
      s += __shfl_xor(s, 16, 64);
      v[mt][r] = s;
    }

  if ((lane & 31) == 0) {
#pragma unroll
    for (int mt = 0; mt < 2; ++mt)
#pragma unroll
      for (int r = 0; r < 16; ++r)
        rowsum[wc2][(wr4 * 2 + mt) * 32 + (r & 3) + 8 * (r >> 2) + 4 * hi] = v[mt][r];
  }
  __syncthreads();

  if (t < 256) {
    float p = rowsum[0][t] + rowsum[1][t];
    atomicAdd(&out[tile_m * 256 + t], p);
  }
}

// ---------------- fallback (direct fp32 path, used only if ws too small) ----
typedef float f32x4 __attribute__((ext_vector_type(4)));
struct Stage {
  float4 x0a, x0b, x1a, x1b;
  float4 a0a, a0b, a1a, a1b;
};

__global__ __launch_bounds__(256) void gemm_rowsq(const float* __restrict__ X,
                                                  const float* __restrict__ A,
                                                  float* __restrict__ out) {
  __shared__ __align__(16) __bf16 Xs[128 * 32];
  __shared__ __align__(16) __bf16 As[128 * 32];
  __shared__ float rowsum[2][128];

  const int t    = threadIdx.x;
  const int lane = t & 63;
  const int wid  = t >> 6;
  const int wr   = wid >> 1;
  const int wc   = wid & 1;
  const int l15  = lane & 15;
  const int lg   = lane >> 4;

  unsigned bid = blockIdx.x;
  unsigned swz = (bid & 7) * 256u + (bid >> 3);
  const int tile_m = swz >> 5;
  const int tile_n = swz & 31;

  const int srow = t >> 2;
  const int sc   = t & 3;
  const int cw   = sc ^ ((t >> 3) & 3);
  const int woff = srow * 32 + cw * 8;

  const float* gx = X + (size_t)(tile_m * 128 + srow) * DK + sc * 8;
  const float* ga = A + (size_t)(tile_n * 128 + srow) * DK + sc * 8;

  const int chA  = lg ^ ((l15 >> 1) & 3);
  const int aoff = (wr * 64 + l15) * 32 + chA * 8;
  const int boff = (wc * 64 + l15) * 32 + chA * 8;

  f32x4 acc[4][4] = {};

  auto load_tile = [&](int kt) {
    Stage s;
    const float* px = gx + kt * 32;
    const float* pa = ga + kt * 32;
    s.x0a = *(const float4*)(px);
    s.x0b = *(const float4*)(px + 4);
    s.x1a = *(const float4*)(px + (size_t)64 * DK);
    s.x1b = *(const float4*)(px + (size_t)64 * DK + 4);
    s.a0a = *(const float4*)(pa);
    s.a0b = *(const float4*)(pa + 4);
    s.a1a = *(const float4*)(pa + (size_t)64 * DK);
    s.a1b = *(const float4*)(pa + (size_t)64 * DK + 4);
    return s;
  };

  auto store_stage = [&](const Stage& s) {
    *(bf16x8*)(Xs + woff)            = pack8(s.x0a, s.x0b);
    *(bf16x8*)(Xs + woff + 64 * 32)  = pack8(s.x1a, s.x1b);
    *(bf16x8*)(As + woff)            = pack8(s.a0a, s.a0b);
    *(bf16x8*)(As + woff + 64 * 32)  = pack8(s.a1a, s.a1b);
  };

  auto compute = [&]() {
    bf16x8 af[4], bfr[4];
#pragma unroll
    for (int m = 0; m < 4; ++m)
      af[m] = *(const bf16x8*)(Xs + aoff + m * 16 * 32);
#pragma unroll
    for (int n = 0; n < 4; ++n)
      bfr[n] = *(const bf16x8*)(As + boff + n * 16 * 32);
#pragma unroll
    for (int m = 0; m < 4; ++m)
#pragma unroll
      for (int n = 0; n < 4; ++n)
        acc[m][n] = __builtin_amdgcn_mfma_f32_16x16x32_bf16(af[m], bfr[n],
                                                            acc[m][n], 0, 0, 0);
  };

  Stage sa = load_tile(0), sb;

  for (int kt = 0; kt < 128; kt += 2) {
    __syncthreads();
    store_stage(sa);
    sb = load_tile(kt + 1);
    __syncthreads();
    compute();
    __syncthreads();
    store_stage(sb);
    if (kt + 2 < 128) sa = load_tile(kt + 2);
    __syncthreads();
    compute();
  }

  float v[4][4];
#pragma unroll
  for (int m = 0; m < 4; ++m)
#pragma unroll
    for (int j = 0; j < 4; ++j) {
      float s = 0.f;
#pragma unroll
      for (int n = 0; n < 4; ++n) {
        float c = acc[m][n][j];
        s += c * c;
      }
      s += __shfl_xor(s, 1, 64);
      s += __shfl_xor(s, 2, 64);
      s += __shfl_xor(s, 4, 64);
      s += __shfl_xor(s, 8, 64);
      v[m][j] = s;
    }

  if (l15 == 0) {
#pragma unroll
    for (int m = 0; m < 4; ++m)
#pragma unroll
      for (int j = 0; j < 4; ++j)
        rowsum[wc][wr * 64 + m * 16 + lg * 4 + j] = v[m][j];
  }
  __syncthreads();

  if (t < 128) {
    float p = rowsum[0][t] + rowsum[1][t];
    atomicAdd(&out[tile_m * 128 + t], p);
  }
}

extern "C" void kernel_launch(void* const* d_in, const int* in_sizes, int n_in,
                              void* d_out, int out_size, void* d_ws, size_t ws_size,
                              hipStream_t stream) {
  const float* x = (const float*)d_in[0];
  const float* A = (const float*)d_in[1];
  float* out = (float*)d_out;

  hipMemsetAsync(out, 0, (size_t)out_size * sizeof(float), stream);

  if (ws_size >= WS_NEED) {
    __bf16* wsX = (__bf16*)d_ws;
    __bf16* wsW = wsX + X_ELEMS;
    hipLaunchKernelGGL(conv32, dim3(2048), dim3(256), 0, stream, x, wsX, X_TILES);
    hipLaunchKernelGGL(conv32, dim3(2048), dim3(256), 0, stream, A, wsW, W_TILES);
    hipLaunchKernelGGL(gemm13, dim3(512), dim3(512), 0, stream, wsX, wsW, out);
  } else {
    hipLaunchKernelGGL(gemm_rowsq, dim3(2048), dim3(256), 0, stream, x, A, out);
  }
}

// Round 11
// 313.718 us; speedup vs baseline: 24.4305x; 24.4305x over previous
//
#include <hip/hip_runtime.h>

typedef __bf16 bf16x8 __attribute__((ext_vector_type(8)));
typedef float  f32x16 __attribute__((ext_vector_type(16)));

#define NROWS 8192
#define DK    4096
#define MCOLS 4096
#define NKT   64            // K-tiles of BK=64
#define IMG   16384         // bf16 elems per 256x64 tile image (32 KB)
#define X_TILES 32
#define W_TILES 16

#define X_ELEMS ((size_t)NROWS * DK)
#define A_ELEMS ((size_t)MCOLS * DK)
#define WS_NEED ((X_ELEMS + A_ELEMS) * 2)

#define BAR()  do { __builtin_amdgcn_s_barrier(); asm volatile("" ::: "memory"); } while (0)
#define LGKM0  asm volatile("s_waitcnt lgkmcnt(0)" ::: "memory")
#define VM(n)  asm volatile("s_waitcnt vmcnt(" #n ")" ::: "memory")

__device__ __forceinline__ bf16x8 pack8(const float4& a, const float4& b) {
  bf16x8 r;
  r[0] = (__bf16)a.x; r[1] = (__bf16)a.y; r[2] = (__bf16)a.z; r[3] = (__bf16)a.w;
  r[4] = (__bf16)b.x; r[5] = (__bf16)b.y; r[6] = (__bf16)b.z; r[7] = (__bf16)b.w;
  return r;
}

__device__ __forceinline__ void gload16(const __bf16* g, __bf16* l) {
  __builtin_amdgcn_global_load_lds(
      (const __attribute__((address_space(1))) void*)g,
      (__attribute__((address_space(3))) void*)l, 16, 0, 0);
}

// kh-major 32x32-fragment image: [tile][kt][kh 0..1][frag 0..7][ks2 0..1][lane][8]
// element (lane,j) = src[tile*256 + frag*32 + (lane&31)][kt*64 + (kh*2+ks2)*16 + (lane>>5)*8 + j]
// Region 0 (first 8192 elems) = kh0 of ALL frags; region 1 = kh1.
__global__ __launch_bounds__(256) void conv32(const float* __restrict__ src,
                                              __bf16* __restrict__ dst,
                                              int ntiles) {
  const int total = ntiles * NKT * 2048;
  for (int i = blockIdx.x * blockDim.x + threadIdx.x; i < total;
       i += gridDim.x * blockDim.x) {
    int lane = i & 63;
    int ks2  = (i >> 6) & 1;
    int frag = (i >> 7) & 7;
    int kh   = (i >> 10) & 1;
    int kt   = (i >> 11) & 63;
    int tm   = i >> 17;
    int row = tm * 256 + frag * 32 + (lane & 31);
    int k   = kt * 64 + (kh * 2 + ks2) * 16 + (lane >> 5) * 8;
    const float4* p = (const float4*)(src + (size_t)row * DK + k);
    float4 a = p[0], b = p[1];
    *(bf16x8*)(dst + (size_t)i * 8) = pack8(a, b);
  }
}

// ---- R5's verified 8-phase 256^2 schedule, 32x32x16 MFMA data plane --------
__global__ __launch_bounds__(512, 2) void gemm14(const __bf16* __restrict__ wsX,
                                                 const __bf16* __restrict__ wsW,
                                                 float* __restrict__ out) {
  __shared__ __align__(16) __bf16 Xls[2][IMG];   // 64 KB
  __shared__ __align__(16) __bf16 Wls[2][IMG];   // 64 KB
  __shared__ float rowsum[2][256];

  const int t    = threadIdx.x;
  const int lane = t & 63;
  const int w    = t >> 6;           // 0..7
  const int wr4  = w >> 1;           // 0..3 : rows wr4*64..+63 (frags 2wr4, 2wr4+1)
  const int wc2  = w & 1;            // 0..1 : cols wc2*128..+127 (frags wc2*4..+3)
  const int hi   = lane >> 5;

  // XCD L2-window mapping (R5-verified): each XCD an 8m x 8n region
  unsigned bid = blockIdx.x;
  unsigned xcd = bid & 7, seq = bid >> 3;
  const int tile_m = (int)((xcd >> 1) * 8 + (seq & 7));    // 0..31
  const int tile_n = (int)((xcd & 1) * 8 + (seq >> 3));    // 0..15

  const __bf16* xbase = wsX + (size_t)tile_m * ((size_t)NKT * IMG);
  const __bf16* wbase = wsW + (size_t)tile_n * ((size_t)NKT * IMG);

  const __bf16* pX0 = &Xls[0][0] + lane * 8;
  const __bf16* pX1 = &Xls[1][0] + lane * 8;
  const __bf16* pW0 = &Wls[0][0] + lane * 8;
  const __bf16* pW1 = &Wls[1][0] + lane * 8;

  f32x16 acc[2][4] = {};     // [mt][nf] : 128 VGPR
  bf16x8 a[2][2];            // [mt][ks2]
  bf16x8 b0[2][2], b1[2][2]; // [nf2][ks2]

  auto readA = [&](const __bf16* p, int kh) {        // 4 ds_read_b128
#pragma unroll
    for (int mt = 0; mt < 2; ++mt)
#pragma unroll
      for (int ks2 = 0; ks2 < 2; ++ks2)
        a[mt][ks2] = *(const bf16x8*)(p + kh * 8192 +
                                      (wr4 * 2 + mt) * 1024 + ks2 * 512);
  };

  auto readB = [&](bf16x8 (&b)[2][2], const __bf16* p, int kh, int nh2) {  // 4
#pragma unroll
    for (int nf2 = 0; nf2 < 2; ++nf2)
#pragma unroll
      for (int ks2 = 0; ks2 < 2; ++ks2)
        b[nf2][ks2] = *(const bf16x8*)(p + kh * 8192 +
                                       (wc2 * 4 + nh2 * 2 + nf2) * 1024 + ks2 * 512);
  };

  auto quad = [&](const bf16x8 (&b)[2][2], int nh2) {  // 8 MFMA 32x32x16
    __builtin_amdgcn_s_setprio(1);
#pragma unroll
    for (int ks2 = 0; ks2 < 2; ++ks2)
#pragma unroll
      for (int mt = 0; mt < 2; ++mt)
#pragma unroll
        for (int nf2 = 0; nf2 < 2; ++nf2)
          acc[mt][nh2 * 2 + nf2] = __builtin_amdgcn_mfma_f32_32x32x16_bf16(
              a[mt][ks2], b[nf2][ks2], acc[mt][nh2 * 2 + nf2], 0, 0, 0);
    __builtin_amdgcn_s_setprio(0);
  };

  auto stage = [&](const __bf16* srcImg, int regionOff, __bf16* ldsImg) {
    const __bf16* s0 = srcImg + regionOff + t * 8;
    __bf16* d0 = ldsImg + regionOff + w * 512;   // wave-uniform dst
    gload16(s0, d0);
    gload16(s0 + 4096, d0 + 4096);
  };

  // prologue (R5-verified FIFO): 6 region-stages, VM(8) keeps X0(0),W0(0) forced
  stage(xbase,          0, &Xls[0][0]);   // X0(0)
  stage(wbase,          0, &Wls[0][0]);   // W0(0)
  stage(xbase,       8192, &Xls[0][0]);   // X1(0)
  stage(wbase,       8192, &Wls[0][0]);   // W1(0)
  stage(xbase + IMG,    0, &Xls[1][0]);   // X0(1)
  stage(wbase + IMG,    0, &Wls[1][0]);   // W0(1)
  VM(8);
  BAR();

  for (int it = 0; it < 31; ++it) {
    const int h0 = 2 * it;
    const __bf16* xi1 = xbase + (size_t)(h0 + 1) * IMG;
    const __bf16* wi1 = wbase + (size_t)(h0 + 1) * IMG;
    const __bf16* xi2 = xbase + (size_t)(h0 + 2) * IMG;
    const __bf16* wi2 = wbase + (size_t)(h0 + 2) * IMG;
    const __bf16* xi3 = xbase + (size_t)(h0 + 3) * IMG;
    const __bf16* wi3 = wbase + (size_t)(h0 + 3) * IMG;

    // ---- half-iter A: tile h0 in buf0 ----
    readA(pX0, 0); readB(b0, pW0, 0, 0);
    stage(xi1, 8192, &Xls[1][0]);                 // X1(h0+1)
    BAR(); LGKM0; quad(b0, 0); VM(6); BAR();      // forces X1,W1(h0)
    readB(b1, pW0, 0, 1);
    stage(wi1, 8192, &Wls[1][0]);                 // W1(h0+1)
    BAR(); LGKM0; quad(b1, 1); BAR();
    readA(pX0, 1); readB(b0, pW0, 1, 0);
    stage(xi2, 0, &Xls[0][0]);                    // X0(h0+2)
    BAR(); LGKM0; quad(b0, 0); BAR();
    readB(b1, pW0, 1, 1);
    stage(wi2, 0, &Wls[0][0]);                    // W0(h0+2)
    BAR(); LGKM0; quad(b1, 1); VM(8); BAR();      // forces X0,W0(h0+1)

    // ---- half-iter B: tile h0+1 in buf1 ----
    readA(pX1, 0); readB(b0, pW1, 0, 0);
    stage(xi2, 8192, &Xls[0][0]);                 // X1(h0+2)
    BAR(); LGKM0; quad(b0, 0); VM(6); BAR();      // forces X1,W1(h0+1)
    readB(b1, pW1, 0, 1);
    stage(wi2, 8192, &Wls[0][0]);                 // W1(h0+2)
    BAR(); LGKM0; quad(b1, 1); BAR();
    readA(pX1, 1); readB(b0, pW1, 1, 0);
    stage(xi3, 0, &Xls[1][0]);                    // X0(h0+3)
    BAR(); LGKM0; quad(b0, 0); BAR();
    readB(b1, pW1, 1, 1);
    stage(wi3, 0, &Wls[1][0]);                    // W0(h0+3)
    BAR(); LGKM0; quad(b1, 1); VM(8); BAR();      // forces X0,W0(h0+2)
  }

  // ---- peeled tail: it = 31 (tiles 62 in buf0, 63 in buf1) ----
  {
    const __bf16* xi1 = xbase + (size_t)63 * IMG;
    const __bf16* wi1 = wbase + (size_t)63 * IMG;

    readA(pX0, 0); readB(b0, pW0, 0, 0);
    stage(xi1, 8192, &Xls[1][0]);                 // X1(63)
    BAR(); LGKM0; quad(b0, 0); VM(6); BAR();      // forces X1,W1(62)
    readB(b1, pW0, 0, 1);
    stage(wi1, 8192, &Wls[1][0]);                 // W1(63)
    BAR(); LGKM0; quad(b1, 1); BAR();
    readA(pX0, 1); readB(b0, pW0, 1, 0);
    BAR(); LGKM0; quad(b0, 0); BAR();
    readB(b1, pW0, 1, 1);
    BAR(); LGKM0; quad(b1, 1); VM(4); BAR();      // forces X0,W0(63)
    readA(pX1, 0); readB(b0, pW1, 0, 0);
    BAR(); LGKM0; quad(b0, 0); VM(0); BAR();      // forces X1,W1(63)
    readB(b1, pW1, 0, 1);
    BAR(); LGKM0; quad(b1, 1); BAR();
    readA(pX1, 1); readB(b0, pW1, 1, 0);
    BAR(); LGKM0; quad(b0, 0); BAR();
    readB(b1, pW1, 1, 1);
    LGKM0; quad(b1, 1);
  }

  // ---- epilogue: row sums of squares (R9-verified 32x32 C/D mapping) ----
  // acc[mt][nf] reg r: row = tile_m*256 + (wr4*2+mt)*32 + (r&3) + 8*(r>>2) + 4*hi
  float v[2][16];
#pragma unroll
  for (int mt = 0; mt < 2; ++mt)
#pragma unroll
    for (int r = 0; r < 16; ++r) {
      float s = 0.f;
#pragma unroll
      for (int nf = 0; nf < 4; ++nf) {
        float c = acc[mt][nf][r];
        s += c * c;
      }
      s += __shfl_xor(s, 1, 64);
      s += __shfl_xor(s, 2, 64);
      s += __shfl_xor(s, 4, 64);
      s += __shfl_xor(s, 8, 64);
      s += __shfl_xor(s, 16, 64);
      v[mt][r] = s;
    }

  if ((lane & 31) == 0) {
#pragma unroll
    for (int mt = 0; mt < 2; ++mt)
#pragma unroll
      for (int r = 0; r < 16; ++r)
        rowsum[wc2][(wr4 * 2 + mt) * 32 + (r & 3) + 8 * (r >> 2) + 4 * hi] = v[mt][r];
  }
  __syncthreads();

  if (t < 256) {
    float p = rowsum[0][t] + rowsum[1][t];
    atomicAdd(&out[tile_m * 256 + t], p);
  }
}

// ---------------- fallback (direct fp32 path, used only if ws too small) ----
typedef float f32x4 __attribute__((ext_vector_type(4)));
struct Stage {
  float4 x0a, x0b, x1a, x1b;
  float4 a0a, a0b, a1a, a1b;
};

__global__ __launch_bounds__(256) void gemm_rowsq(const float* __restrict__ X,
                                                  const float* __restrict__ A,
                                                  float* __restrict__ out) {
  __shared__ __align__(16) __bf16 Xs[128 * 32];
  __shared__ __align__(16) __bf16 As[128 * 32];
  __shared__ float rowsum[2][128];

  const int t    = threadIdx.x;
  const int lane = t & 63;
  const int wid  = t >> 6;
  const int wr   = wid >> 1;
  const int wc   = wid & 1;
  const int l15  = lane & 15;
  const int lg   = lane >> 4;

  unsigned bid = blockIdx.x;
  unsigned swz = (bid & 7) * 256u + (bid >> 3);
  const int tile_m = swz >> 5;
  const int tile_n = swz & 31;

  const int srow = t >> 2;
  const int sc   = t & 3;
  const int cw   = sc ^ ((t >> 3) & 3);
  const int woff = srow * 32 + cw * 8;

  const float* gx = X + (size_t)(tile_m * 128 + srow) * DK + sc * 8;
  const float* ga = A + (size_t)(tile_n * 128 + srow) * DK + sc * 8;

  const int chA  = lg ^ ((l15 >> 1) & 3);
  const int aoff = (wr * 64 + l15) * 32 + chA * 8;
  const int boff = (wc * 64 + l15) * 32 + chA * 8;

  f32x4 acc[4][4] = {};

  auto load_tile = [&](int kt) {
    Stage s;
    const float* px = gx + kt * 32;
    const float* pa = ga + kt * 32;
    s.x0a = *(const float4*)(px);
    s.x0b = *(const float4*)(px + 4);
    s.x1a = *(const float4*)(px + (size_t)64 * DK);
    s.x1b = *(const float4*)(px + (size_t)64 * DK + 4);
    s.a0a = *(const float4*)(pa);
    s.a0b = *(const float4*)(pa + 4);
    s.a1a = *(const float4*)(pa + (size_t)64 * DK);
    s.a1b = *(const float4*)(pa + (size_t)64 * DK + 4);
    return s;
  };

  auto store_stage = [&](const Stage& s) {
    *(bf16x8*)(Xs + woff)            = pack8(s.x0a, s.x0b);
    *(bf16x8*)(Xs + woff + 64 * 32)  = pack8(s.x1a, s.x1b);
    *(bf16x8*)(As + woff)            = pack8(s.a0a, s.a0b);
    *(bf16x8*)(As + woff + 64 * 32)  = pack8(s.a1a, s.a1b);
  };

  auto compute = [&]() {
    bf16x8 af[4], bfr[4];
#pragma unroll
    for (int m = 0; m < 4; ++m)
      af[m] = *(const bf16x8*)(Xs + aoff + m * 16 * 32);
#pragma unroll
    for (int n = 0; n < 4; ++n)
      bfr[n] = *(const bf16x8*)(As + boff + n * 16 * 32);
#pragma unroll
    for (int m = 0; m < 4; ++m)
#pragma unroll
      for (int n = 0; n < 4; ++n)
        acc[m][n] = __builtin_amdgcn_mfma_f32_16x16x32_bf16(af[m], bfr[n],
                                                            acc[m][n], 0, 0, 0);
  };

  Stage sa = load_tile(0), sb;

  for (int kt = 0; kt < 128; kt += 2) {
    __syncthreads();
    store_stage(sa);
    sb = load_tile(kt + 1);
    __syncthreads();
    compute();
    __syncthreads();
    store_stage(sb);
    if (kt + 2 < 128) sa = load_tile(kt + 2);
    __syncthreads();
    compute();
  }

  float v[4][4];
#pragma unroll
  for (int m = 0; m < 4; ++m)
#pragma unroll
    for (int j = 0; j < 4; ++j) {
      float s = 0.f;
#pragma unroll
      for (int n = 0; n < 4; ++n) {
        float c = acc[m][n][j];
        s += c * c;
      }
      s += __shfl_xor(s, 1, 64);
      s += __shfl_xor(s, 2, 64);
      s += __shfl_xor(s, 4, 64);
      s += __shfl_xor(s, 8, 64);
      v[m][j] = s;
    }

  if (l15 == 0) {
#pragma unroll
    for (int m = 0; m < 4; ++m)
#pragma unroll
      for (int j = 0; j < 4; ++j)
        rowsum[wc][wr * 64 + m * 16 + lg * 4 + j] = v[m][j];
  }
  __syncthreads();

  if (t < 128) {
    float p = rowsum[0][t] + rowsum[1][t];
    atomicAdd(&out[tile_m * 128 + t], p);
  }
}

extern "C" void kernel_launch(void* const* d_in, const int* in_sizes, int n_in,
                              void* d_out, int out_size, void* d_ws, size_t ws_size,
                              hipStream_t stream) {
  const float* x = (const float*)d_in[0];
  const float* A = (const float*)d_in[1];
  float* out = (float*)d_out;

  hipMemsetAsync(out, 0, (size_t)out_size * sizeof(float), stream);

  if (ws_size >= WS_NEED) {
    __bf16* wsX = (__bf16*)d_ws;
    __bf16* wsW = wsX + X_ELEMS;
    hipLaunchKernelGGL(conv32, dim3(2048), dim3(256), 0, stream, x, wsX, X_TILES);
    hipLaunchKernelGGL(conv32, dim3(2048), dim3(256), 0, stream, A, wsW, W_TILES);
    hipLaunchKernelGGL(gemm14, dim3(512), dim3(512), 0, stream, wsX, wsW, out);
  } else {
    hipLaunchKernelGGL(gemm_rowsq, dim3(2048), dim3(256), 0, stream, x, A, out);
  }
}

// Round 12
// 268.685 us; speedup vs baseline: 28.5252x; 1.1676x over previous
//
#include <hip/hip_runtime.h>

typedef __bf16 bf16x8 __attribute__((ext_vector_type(8)));
typedef float  f32x4  __attribute__((ext_vector_type(4)));

#define NROWS 8192
#define DK    4096
#define MCOLS 4096
#define NKT   64            // K-tiles of BK=64
#define IMG   16384         // bf16 elems per 256x64 tile image (32 KB)
#define X_TILES 32
#define W_TILES 16

#define X_ELEMS ((size_t)NROWS * DK)
#define A_ELEMS ((size_t)MCOLS * DK)
#define WS_NEED ((X_ELEMS + A_ELEMS) * 2)

#define BAR()  do { __builtin_amdgcn_s_barrier(); asm volatile("" ::: "memory"); } while (0)
#define LGKM0  asm volatile("s_waitcnt lgkmcnt(0)" ::: "memory")
#define VM(n)  asm volatile("s_waitcnt vmcnt(" #n ")" ::: "memory")

__device__ __forceinline__ bf16x8 pack8(const float4& a, const float4& b) {
  bf16x8 r;
  r[0] = (__bf16)a.x; r[1] = (__bf16)a.y; r[2] = (__bf16)a.z; r[3] = (__bf16)a.w;
  r[4] = (__bf16)b.x; r[5] = (__bf16)b.y; r[6] = (__bf16)b.z; r[7] = (__bf16)b.w;
  return r;
}

__device__ __forceinline__ void gload16(const __bf16* g, __bf16* l) {
  __builtin_amdgcn_global_load_lds(
      (const __attribute__((address_space(1))) void*)g,
      (__attribute__((address_space(3))) void*)l, 16, 0, 0);
}

// ---- converts (R5-verified): fp32 row-major -> bf16 fragment-major images --
// X image slot = mh*8 + wr4*2 + m2  (m_frag = wr4*4 + mh*2 + m2)
__global__ __launch_bounds__(256) void convX(const float* __restrict__ src,
                                             __bf16* __restrict__ dst) {
  const int total = X_TILES * NKT * 2048;
  for (int i = blockIdx.x * blockDim.x + threadIdx.x; i < total;
       i += gridDim.x * blockDim.x) {
    int lane = i & 63;
    int kc   = (i >> 6) & 1;
    int slot = (i >> 7) & 15;
    int kt   = (i >> 11) & 63;
    int tm   = i >> 17;
    int mh = slot >> 3, wr4 = (slot >> 1) & 3, m2 = slot & 1;
    int mfrag = wr4 * 4 + mh * 2 + m2;
    int row = tm * 256 + mfrag * 16 + (lane & 15);
    int k   = kt * 64 + kc * 32 + (lane >> 4) * 8;
    const float4* p = (const float4*)(src + (size_t)row * DK + k);
    float4 a = p[0], b = p[1];
    *(bf16x8*)(dst + (size_t)i * 8) = pack8(a, b);
  }
}

// W image slot = nh*8 + wc2*4 + n4  (n_frag = wc2*8 + nh*4 + n4)
__global__ __launch_bounds__(256) void convW(const float* __restrict__ src,
                                             __bf16* __restrict__ dst) {
  const int total = W_TILES * NKT * 2048;
  for (int i = blockIdx.x * blockDim.x + threadIdx.x; i < total;
       i += gridDim.x * blockDim.x) {
    int lane = i & 63;
    int kc   = (i >> 6) & 1;
    int slot = (i >> 7) & 15;
    int kt   = (i >> 11) & 63;
    int tn   = i >> 17;
    int nh = slot >> 3, wc2 = (slot >> 2) & 1, n4 = slot & 3;
    int nfrag = wc2 * 8 + nh * 4 + n4;
    int row = tn * 256 + nfrag * 16 + (lane & 15);
    int k   = kt * 64 + kc * 32 + (lane >> 4) * 8;
    const float4* p = (const float4*)(src + (size_t)row * DK + k);
    float4 a = p[0], b = p[1];
    *(bf16x8*)(dst + (size_t)i * 8) = pack8(a, b);
  }
}

// ---- R5 gemm8 with FIFO-ordered staging + non-blocking counted vmcnt -------
__device__ __forceinline__ void readA(bf16x8 (&a)[2][2], const __bf16* p, int MH) {
#pragma unroll
  for (int m2 = 0; m2 < 2; ++m2)
#pragma unroll
    for (int kc = 0; kc < 2; ++kc)
      a[m2][kc] = *(const bf16x8*)(p + MH * 8192 + m2 * 1024 + kc * 512);
}

__device__ __forceinline__ void readB(bf16x8 (&b)[4][2], const __bf16* p, int NH) {
#pragma unroll
  for (int n4 = 0; n4 < 4; ++n4)
#pragma unroll
    for (int kc = 0; kc < 2; ++kc)
      b[n4][kc] = *(const bf16x8*)(p + NH * 8192 + n4 * 1024 + kc * 512);
}

__device__ __forceinline__ void quad(f32x4 (&acc)[4][8], const bf16x8 (&a)[2][2],
                                     const bf16x8 (&b)[4][2], int MH, int NH) {
  __builtin_amdgcn_s_setprio(1);
#pragma unroll
  for (int m2 = 0; m2 < 2; ++m2)
#pragma unroll
    for (int n4 = 0; n4 < 4; ++n4)
#pragma unroll
      for (int kc = 0; kc < 2; ++kc)
        acc[MH * 2 + m2][NH * 4 + n4] = __builtin_amdgcn_mfma_f32_16x16x32_bf16(
            a[m2][kc], b[n4][kc], acc[MH * 2 + m2][NH * 4 + n4], 0, 0, 0);
  __builtin_amdgcn_s_setprio(0);
}

__global__ __launch_bounds__(512, 2) void gemm15(const __bf16* __restrict__ wsX,
                                                 const __bf16* __restrict__ wsW,
                                                 float* __restrict__ out) {
  __shared__ __align__(16) __bf16 Xls[2][IMG];   // 64 KB
  __shared__ __align__(16) __bf16 Wls[2][IMG];   // 64 KB
  __shared__ float rowsum[2][256];

  const int t    = threadIdx.x;
  const int lane = t & 63;
  const int w    = t >> 6;           // 0..7
  const int wr4  = w >> 1;           // rows wr4*64..+63
  const int wc2  = w & 1;            // cols wc2*128..+127
  const int l15  = lane & 15;
  const int lg   = lane >> 4;

  // XCD L2-window mapping (R5-verified)
  unsigned bid = blockIdx.x;
  unsigned xcd = bid & 7, seq = bid >> 3;
  const int tile_m = (int)((xcd >> 1) * 8 + (seq & 7));    // 0..31
  const int tile_n = (int)((xcd & 1) * 8 + (seq >> 3));    // 0..15

  const __bf16* xbase = wsX + (size_t)tile_m * ((size_t)NKT * IMG);
  const __bf16* wbase = wsW + (size_t)tile_n * ((size_t)NKT * IMG);

  const __bf16* pX0 = &Xls[0][0] + wr4 * 2048 + lane * 8;
  const __bf16* pX1 = &Xls[1][0] + wr4 * 2048 + lane * 8;
  const __bf16* pW0 = &Wls[0][0] + wc2 * 4096 + lane * 8;
  const __bf16* pW1 = &Wls[1][0] + wc2 * 4096 + lane * 8;

  f32x4 acc[4][8] = {};
  bf16x8 a[2][2], b0[4][2], b1[4][2];

  auto stage = [&](const __bf16* srcImg, int regionOff, __bf16* ldsImg) {
    const __bf16* s0 = srcImg + regionOff + t * 8;
    __bf16* d0 = ldsImg + regionOff + w * 512;   // wave-uniform dst
    gload16(s0, d0);
    gload16(s0 + 4096, d0 + 4096);
  };

  // prologue: FIFO = consumption order. Forced set after VM(8): X0(0),W0(0).
  stage(xbase,          0, &Xls[0][0]);   // X0(0)
  stage(wbase,          0, &Wls[0][0]);   // W0(0)
  stage(wbase,       8192, &Wls[0][0]);   // W1(0)
  stage(xbase,       8192, &Xls[0][0]);   // X1(0)
  stage(xbase + IMG,    0, &Xls[1][0]);   // X0(1)
  stage(wbase + IMG,    0, &Wls[1][0]);   // W0(1)
  VM(8);
  BAR();

  for (int it = 0; it < 31; ++it) {
    const int h0 = 2 * it;
    const __bf16* xi1 = xbase + (size_t)(h0 + 1) * IMG;
    const __bf16* wi1 = wbase + (size_t)(h0 + 1) * IMG;
    const __bf16* xi2 = xbase + (size_t)(h0 + 2) * IMG;
    const __bf16* wi2 = wbase + (size_t)(h0 + 2) * IMG;
    const __bf16* xi3 = xbase + (size_t)(h0 + 3) * IMG;
    const __bf16* wi3 = wbase + (size_t)(h0 + 3) * IMG;

    // ---- half-iter A: tile h0 in buf0 ----
    // p1: stage W1(h0+1) FIRST (consumed first next tile)
    readA(a, pX0, 0); readB(b0, pW0, 0);
    stage(wi1, 8192, &Wls[1][0]);
    BAR(); LGKM0; quad(acc, a, b0, 0, 0); VM(8); BAR();   // forces W1(h0), age 5ph
    // p2
    readB(b1, pW0, 1);
    stage(xi1, 8192, &Xls[1][0]);
    BAR(); LGKM0; quad(acc, a, b1, 0, 1); VM(8); BAR();   // forces X1(h0), age 5ph
    // p3
    readA(a, pX0, 1);
    stage(xi2, 0, &Xls[0][0]);
    BAR(); LGKM0; quad(acc, a, b0, 1, 0); BAR();
    // p4
    stage(wi2, 0, &Wls[0][0]);
    BAR(); quad(acc, a, b1, 1, 1); VM(8); BAR();          // forces X0,W0(h0+1)

    // ---- half-iter B: tile h0+1 in buf1 ----
    // p5
    readA(a, pX1, 0); readB(b0, pW1, 0);
    stage(wi2, 8192, &Wls[0][0]);
    BAR(); LGKM0; quad(acc, a, b0, 0, 0); VM(8); BAR();   // forces W1(h0+1)
    // p6
    readB(b1, pW1, 1);
    stage(xi2, 8192, &Xls[0][0]);
    BAR(); LGKM0; quad(acc, a, b1, 0, 1); VM(8); BAR();   // forces X1(h0+1)
    // p7
    readA(a, pX1, 1);
    stage(xi3, 0, &Xls[1][0]);
    BAR(); LGKM0; quad(acc, a, b0, 1, 0); BAR();
    // p8
    stage(wi3, 0, &Wls[1][0]);
    BAR(); quad(acc, a, b1, 1, 1); VM(8); BAR();          // forces X0,W0(h0+2)
  }

  // ---- peeled tail: it = 31 (tiles 62 in buf0, 63 in buf1) ----
  {
    const __bf16* xi1 = xbase + (size_t)63 * IMG;
    const __bf16* wi1 = wbase + (size_t)63 * IMG;

    // p1
    readA(a, pX0, 0); readB(b0, pW0, 0);
    stage(wi1, 8192, &Wls[1][0]);                 // W1(63)
    BAR(); LGKM0; quad(acc, a, b0, 0, 0); VM(8); BAR();   // forces W1(62)
    // p2
    readB(b1, pW0, 1);
    stage(xi1, 8192, &Xls[1][0]);                 // X1(63)
    BAR(); LGKM0; quad(acc, a, b1, 0, 1); VM(8); BAR();   // forces X1(62)
    // p3
    readA(a, pX0, 1);
    BAR(); LGKM0; quad(acc, a, b0, 1, 0); BAR();
    // p4
    BAR(); quad(acc, a, b1, 1, 1); VM(4); BAR();  // forces X0,W0(63)
    // p5
    readA(a, pX1, 0); readB(b0, pW1, 0);
    BAR(); LGKM0; quad(acc, a, b0, 0, 0); VM(2); BAR();   // forces W1(63)
    // p6
    readB(b1, pW1, 1);
    BAR(); LGKM0; quad(acc, a, b1, 0, 1); VM(0); BAR();   // forces X1(63)
    // p7
    readA(a, pX1, 1);
    BAR(); LGKM0; quad(acc, a, b0, 1, 0); BAR();
    // p8
    quad(acc, a, b1, 1, 1);
  }

  // ---- epilogue: row sums of squares (R5-verified mapping) ----
  float v[4][4];
#pragma unroll
  for (int mr = 0; mr < 4; ++mr)
#pragma unroll
    for (int j = 0; j < 4; ++j) {
      float s = 0.f;
#pragma unroll
      for (int nc = 0; nc < 8; ++nc) {
        float c = acc[mr][nc][j];
        s += c * c;
      }
      s += __shfl_xor(s, 1, 64);
      s += __shfl_xor(s, 2, 64);
      s += __shfl_xor(s, 4, 64);
      s += __shfl_xor(s, 8, 64);
      v[mr][j] = s;
    }

  if (l15 == 0) {
#pragma unroll
    for (int mr = 0; mr < 4; ++mr)
#pragma unroll
      for (int j = 0; j < 4; ++j)
        rowsum[wc2][(wr4 * 4 + mr) * 16 + lg * 4 + j] = v[mr][j];
  }
  __syncthreads();

  if (t < 256) {
    float p = rowsum[0][t] + rowsum[1][t];
    atomicAdd(&out[tile_m * 256 + t], p);
  }
}

// ---------------- fallback (direct fp32 path, used only if ws too small) ----
struct Stage {
  float4 x0a, x0b, x1a, x1b;
  float4 a0a, a0b, a1a, a1b;
};

__global__ __launch_bounds__(256) void gemm_rowsq(const float* __restrict__ X,
                                                  const float* __restrict__ A,
                                                  float* __restrict__ out) {
  __shared__ __align__(16) __bf16 Xs[128 * 32];
  __shared__ __align__(16) __bf16 As[128 * 32];
  __shared__ float rowsum[2][128];

  const int t    = threadIdx.x;
  const int lane = t & 63;
  const int wid  = t >> 6;
  const int wr   = wid >> 1;
  const int wc   = wid & 1;
  const int l15  = lane & 15;
  const int lg   = lane >> 4;

  unsigned bid = blockIdx.x;
  unsigned swz = (bid & 7) * 256u + (bid >> 3);
  const int tile_m = swz >> 5;
  const int tile_n = swz & 31;

  const int srow = t >> 2;
  const int sc   = t & 3;
  const int cw   = sc ^ ((t >> 3) & 3);
  const int woff = srow * 32 + cw * 8;

  const float* gx = X + (size_t)(tile_m * 128 + srow) * DK + sc * 8;
  const float* ga = A + (size_t)(tile_n * 128 + srow) * DK + sc * 8;

  const int chA  = lg ^ ((l15 >> 1) & 3);
  const int aoff = (wr * 64 + l15) * 32 + chA * 8;
  const int boff = (wc * 64 + l15) * 32 + chA * 8;

  f32x4 acc[4][4] = {};

  auto load_tile = [&](int kt) {
    Stage s;
    const float* px = gx + kt * 32;
    const float* pa = ga + kt * 32;
    s.x0a = *(const float4*)(px);
    s.x0b = *(const float4*)(px + 4);
    s.x1a = *(const float4*)(px + (size_t)64 * DK);
    s.x1b = *(const float4*)(px + (size_t)64 * DK + 4);
    s.a0a = *(const float4*)(pa);
    s.a0b = *(const float4*)(pa + 4);
    s.a1a = *(const float4*)(pa + (size_t)64 * DK);
    s.a1b = *(const float4*)(pa + (size_t)64 * DK + 4);
    return s;
  };

  auto store_stage = [&](const Stage& s) {
    *(bf16x8*)(Xs + woff)            = pack8(s.x0a, s.x0b);
    *(bf16x8*)(Xs + woff + 64 * 32)  = pack8(s.x1a, s.x1b);
    *(bf16x8*)(As + woff)            = pack8(s.a0a, s.a0b);
    *(bf16x8*)(As + woff + 64 * 32)  = pack8(s.a1a, s.a1b);
  };

  auto compute = [&]() {
    bf16x8 af[4], bfr[4];
#pragma unroll
    for (int m = 0; m < 4; ++m)
      af[m] = *(const bf16x8*)(Xs + aoff + m * 16 * 32);
#pragma unroll
    for (int n = 0; n < 4; ++n)
      bfr[n] = *(const bf16x8*)(As + boff + n * 16 * 32);
#pragma unroll
    for (int m = 0; m < 4; ++m)
#pragma unroll
      for (int n = 0; n < 4; ++n)
        acc[m][n] = __builtin_amdgcn_mfma_f32_16x16x32_bf16(af[m], bfr[n],
                                                            acc[m][n], 0, 0, 0);
  };

  Stage sa = load_tile(0), sb;

  for (int kt = 0; kt < 128; kt += 2) {
    __syncthreads();
    store_stage(sa);
    sb = load_tile(kt + 1);
    __syncthreads();
    compute();
    __syncthreads();
    store_stage(sb);
    if (kt + 2 < 128) sa = load_tile(kt + 2);
    __syncthreads();
    compute();
  }

  float v[4][4];
#pragma unroll
  for (int m = 0; m < 4; ++m)
#pragma unroll
    for (int j = 0; j < 4; ++j) {
      float s = 0.f;
#pragma unroll
      for (int n = 0; n < 4; ++n) {
        float c = acc[m][n][j];
        s += c * c;
      }
      s += __shfl_xor(s, 1, 64);
      s += __shfl_xor(s, 2, 64);
      s += __shfl_xor(s, 4, 64);
      s += __shfl_xor(s, 8, 64);
      v[m][j] = s;
    }

  if (l15 == 0) {
#pragma unroll
    for (int m = 0; m < 4; ++m)
#pragma unroll
      for (int j = 0; j < 4; ++j)
        rowsum[wc][wr * 64 + m * 16 + lg * 4 + j] = v[m][j];
  }
  __syncthreads();

  if (t < 128) {
    float p = rowsum[0][t] + rowsum[1][t];
    atomicAdd(&out[tile_m * 128 + t], p);
  }
}

extern "C" void kernel_launch(void* const* d_in, const int* in_sizes, int n_in,
                              void* d_out, int out_size, void* d_ws, size_t ws_size,
                              hipStream_t stream) {
  const float* x = (const float*)d_in[0];
  const float* A = (const float*)d_in[1];
  float* out = (float*)d_out;

  hipMemsetAsync(out, 0, (size_t)out_size * sizeof(float), stream);

  if (ws_size >= WS_NEED) {
    __bf16* wsX = (__bf16*)d_ws;
    __bf16* wsW = wsX + X_ELEMS;
    hipLaunchKernelGGL(convX, dim3(2048), dim3(256), 0, stream, x, wsX);
    hipLaunchKernelGGL(convW, dim3(2048), dim3(256), 0, stream, A, wsW);
    hipLaunchKernelGGL(gemm15, dim3(512), dim3(512), 0, stream, wsX, wsW, out);
  } else {
    hipLaunchKernelGGL(gemm_rowsq, dim3(2048), dim3(256), 0, stream, x, A, out);
  }
}

// Round 13
// 166.651 us; speedup vs baseline: 45.9900x; 1.6123x over previous
//
#include <hip/hip_runtime.h>
#include <hip/hip_fp8.h>

typedef __bf16 bf16x8 __attribute__((ext_vector_type(8)));
typedef float  f32x4  __attribute__((ext_vector_type(4)));
typedef float  f32x16 __attribute__((ext_vector_type(16)));
typedef int    i32x4v __attribute__((ext_vector_type(4)));
typedef int    i32x8v __attribute__((ext_vector_type(8)));
typedef unsigned char uchar16v __attribute__((ext_vector_type(16)));

#define NROWS 8192
#define DK    4096
#define MCOLS 4096

// ---- fp8 path geometry: BK=128, tile' images byte-identical to bf16 BK=64 --
#define NKT2   32            // K-tiles of BK=128
#define IMGB   32768         // bytes per 256x128 fp8 tile image (32 KB)
#define REGB   16384         // region bytes (ki half)
#define XT2    32            // 8192/256
#define WT2    16            // 4096/256

#define X_BYTES ((size_t)XT2 * NKT2 * IMGB)   // 33.5 MB
#define W_BYTES ((size_t)WT2 * NKT2 * IMGB)   // 16.8 MB
#define WS_NEED (X_BYTES + W_BYTES)

#define BAR()  do { __builtin_amdgcn_s_barrier(); asm volatile("" ::: "memory"); } while (0)
#define LGKM0  asm volatile("s_waitcnt lgkmcnt(0)" ::: "memory")
#define VM(n)  asm volatile("s_waitcnt vmcnt(" #n ")" ::: "memory")

__device__ __forceinline__ void gload16(const unsigned char* g, unsigned char* l) {
  __builtin_amdgcn_global_load_lds(
      (const __attribute__((address_space(1))) void*)g,
      (__attribute__((address_space(3))) void*)l, 16, 0, 0);
}

// fp32 row-major -> e4m3 fragment image:
// [tile][kt'][ki 0..1][slot 0..7][half 0..1][lane 0..63][16B]
// elem (lane, half*16+jj): row = tile*256 + slot*32 + (lane&31)
//                          k   = kt'*128 + ki*64 + (lane>>5)*32 + half*16 + jj
__global__ __launch_bounds__(256) void convF8(const float* __restrict__ src,
                                              unsigned char* __restrict__ dst,
                                              int ntiles, float scale) {
  const int total = ntiles * 65536;   // (kt 32)(ki 2)(slot 8)(half 2)(lane 64)
  for (int i = blockIdx.x * blockDim.x + threadIdx.x; i < total;
       i += gridDim.x * blockDim.x) {
    int lane = i & 63;
    int half = (i >> 6) & 1;
    int slot = (i >> 7) & 7;
    int ki   = (i >> 10) & 1;
    int kt   = (i >> 11) & 31;
    int tm   = i >> 16;
    int row = tm * 256 + slot * 32 + (lane & 31);
    int k   = kt * 128 + ki * 64 + (lane >> 5) * 32 + half * 16;
    const float4* p = (const float4*)(src + (size_t)row * DK + k);
    uchar16v o;
#pragma unroll
    for (int q = 0; q < 4; ++q) {
      float4 f = p[q];
      o[q * 4 + 0] = __hip_fp8_e4m3(f.x * scale).__x;
      o[q * 4 + 1] = __hip_fp8_e4m3(f.y * scale).__x;
      o[q * 4 + 2] = __hip_fp8_e4m3(f.z * scale).__x;
      o[q * 4 + 3] = __hip_fp8_e4m3(f.w * scale).__x;
    }
    *(uchar16v*)(dst + (size_t)i * 16) = o;
  }
}

// ---- R11-verified 8-phase schedule, fp8 32x32x64 scaled-MFMA data plane ----
__global__ __launch_bounds__(512, 2) void gemm16(const unsigned char* __restrict__ wsX,
                                                 const unsigned char* __restrict__ wsW,
                                                 float* __restrict__ out) {
  __shared__ __align__(16) unsigned char Xls[2][IMGB];   // 64 KB
  __shared__ __align__(16) unsigned char Wls[2][IMGB];   // 64 KB
  __shared__ float rowsum[2][256];

  const int t    = threadIdx.x;
  const int lane = t & 63;
  const int w    = t >> 6;           // 0..7
  const int wr4  = w >> 1;           // 0..3 : rows wr4*64..+63 (slots 2wr4,2wr4+1)
  const int wc2  = w & 1;            // 0..1 : cols wc2*128..+127 (slots wc2*4..+3)
  const int hi   = lane >> 5;

  unsigned bid = blockIdx.x;
  unsigned xcd = bid & 7, seq = bid >> 3;
  const int tile_m = (int)((xcd >> 1) * 8 + (seq & 7));    // 0..31
  const int tile_n = (int)((xcd & 1) * 8 + (seq >> 3));    // 0..15

  const unsigned char* xbase = wsX + (size_t)tile_m * ((size_t)NKT2 * IMGB);
  const unsigned char* wbase = wsW + (size_t)tile_n * ((size_t)NKT2 * IMGB);

  const unsigned char* pX0 = &Xls[0][0] + wr4 * 4096 + lane * 16;
  const unsigned char* pX1 = &Xls[1][0] + wr4 * 4096 + lane * 16;
  const unsigned char* pW0 = &Wls[0][0] + wc2 * 8192 + lane * 16;
  const unsigned char* pW1 = &Wls[1][0] + wc2 * 8192 + lane * 16;

  f32x16 acc[2][4] = {};     // [mt][nf] : 128 VGPR
  i32x8v a[2], b0[2], b1[2];

  auto ld32 = [&](const unsigned char* p) {
    i32x4v lo = *(const i32x4v*)p;
    i32x4v hh = *(const i32x4v*)(p + 1024);
    i32x8v r;
    r[0] = lo[0]; r[1] = lo[1]; r[2] = lo[2]; r[3] = lo[3];
    r[4] = hh[0]; r[5] = hh[1]; r[6] = hh[2]; r[7] = hh[3];
    return r;
  };

  auto readA = [&](const unsigned char* p, int ki) {     // 4 ds_read_b128
#pragma unroll
    for (int mt = 0; mt < 2; ++mt)
      a[mt] = ld32(p + ki * REGB + mt * 2048);
  };

  auto readB = [&](i32x8v (&b)[2], const unsigned char* p, int ki, int bh) {  // 4
#pragma unroll
    for (int nf2 = 0; nf2 < 2; ++nf2)
      b[nf2] = ld32(p + ki * REGB + (bh * 2 + nf2) * 2048);
  };

  auto quad = [&](const i32x8v (&b)[2], int bh) {        // 4 MFMA 32x32x64
    __builtin_amdgcn_s_setprio(1);
#pragma unroll
    for (int mt = 0; mt < 2; ++mt)
#pragma unroll
      for (int nf2 = 0; nf2 < 2; ++nf2)
        acc[mt][bh * 2 + nf2] = __builtin_amdgcn_mfma_scale_f32_32x32x64_f8f6f4(
            a[mt], b[nf2], acc[mt][bh * 2 + nf2],
            0, 0,                    // cbsz=FP8(e4m3), blgp=FP8(e4m3)
            0, 0x7F7F7F7F,           // scale A = 1.0 (e8m0 127)
            0, 0x7F7F7F7F);          // scale B = 1.0
    __builtin_amdgcn_s_setprio(0);
  };

  auto stage = [&](const unsigned char* srcImg, int regionOff, unsigned char* ldsImg) {
    const unsigned char* s0 = srcImg + regionOff + t * 16;
    unsigned char* d0 = ldsImg + regionOff + w * 1024;   // wave-uniform dst
    gload16(s0, d0);
    gload16(s0 + 8192, d0 + 8192);
  };

  // prologue (R11-verified FIFO): VM(8) forces X0(0),W0(0)
  stage(xbase,         0,    &Xls[0][0]);   // X0(0)
  stage(wbase,         0,    &Wls[0][0]);   // W0(0)
  stage(xbase,         REGB, &Xls[0][0]);   // X1(0)
  stage(wbase,         REGB, &Wls[0][0]);   // W1(0)
  stage(xbase + IMGB,  0,    &Xls[1][0]);   // X0(1)
  stage(wbase + IMGB,  0,    &Wls[1][0]);   // W0(1)
  VM(8);
  BAR();

  for (int it = 0; it < 15; ++it) {
    const int h0 = 2 * it;
    const unsigned char* xi1 = xbase + (size_t)(h0 + 1) * IMGB;
    const unsigned char* wi1 = wbase + (size_t)(h0 + 1) * IMGB;
    const unsigned char* xi2 = xbase + (size_t)(h0 + 2) * IMGB;
    const unsigned char* wi2 = wbase + (size_t)(h0 + 2) * IMGB;
    const unsigned char* xi3 = xbase + (size_t)(h0 + 3) * IMGB;
    const unsigned char* wi3 = wbase + (size_t)(h0 + 3) * IMGB;

    // ---- half-iter A: tile h0 in buf0 ----
    readA(pX0, 0); readB(b0, pW0, 0, 0);
    stage(xi1, REGB, &Xls[1][0]);                 // X1(h0+1)
    BAR(); LGKM0; quad(b0, 0); VM(6); BAR();      // forces X1,W1(h0)
    readB(b1, pW0, 0, 1);
    stage(wi1, REGB, &Wls[1][0]);                 // W1(h0+1)
    BAR(); LGKM0; quad(b1, 1); BAR();
    readA(pX0, 1); readB(b0, pW0, 1, 0);
    stage(xi2, 0, &Xls[0][0]);                    // X0(h0+2)
    BAR(); LGKM0; quad(b0, 0); BAR();
    readB(b1, pW0, 1, 1);
    stage(wi2, 0, &Wls[0][0]);                    // W0(h0+2)
    BAR(); LGKM0; quad(b1, 1); VM(8); BAR();      // forces X0,W0(h0+1)

    // ---- half-iter B: tile h0+1 in buf1 ----
    readA(pX1, 0); readB(b0, pW1, 0, 0);
    stage(xi2, REGB, &Xls[0][0]);                 // X1(h0+2)
    BAR(); LGKM0; quad(b0, 0); VM(6); BAR();      // forces X1,W1(h0+1)
    readB(b1, pW1, 0, 1);
    stage(wi2, REGB, &Wls[0][0]);                 // W1(h0+2)
    BAR(); LGKM0; quad(b1, 1); BAR();
    readA(pX1, 1); readB(b0, pW1, 1, 0);
    stage(xi3, 0, &Xls[1][0]);                    // X0(h0+3)
    BAR(); LGKM0; quad(b0, 0); BAR();
    readB(b1, pW1, 1, 1);
    stage(wi3, 0, &Wls[1][0]);                    // W0(h0+3)
    BAR(); LGKM0; quad(b1, 1); VM(8); BAR();      // forces X0,W0(h0+2)
  }

  // ---- peeled tail: tiles 30 (buf0), 31 (buf1) ----
  {
    const unsigned char* xi1 = xbase + (size_t)31 * IMGB;
    const unsigned char* wi1 = wbase + (size_t)31 * IMGB;

    readA(pX0, 0); readB(b0, pW0, 0, 0);
    stage(xi1, REGB, &Xls[1][0]);                 // X1(31)
    BAR(); LGKM0; quad(b0, 0); VM(6); BAR();      // forces X1,W1(30)
    readB(b1, pW0, 0, 1);
    stage(wi1, REGB, &Wls[1][0]);                 // W1(31)
    BAR(); LGKM0; quad(b1, 1); BAR();
    readA(pX0, 1); readB(b0, pW0, 1, 0);
    BAR(); LGKM0; quad(b0, 0); BAR();
    readB(b1, pW0, 1, 1);
    BAR(); LGKM0; quad(b1, 1); VM(4); BAR();      // forces X0,W0(31)
    readA(pX1, 0); readB(b0, pW1, 0, 0);
    BAR(); LGKM0; quad(b0, 0); VM(0); BAR();      // forces X1,W1(31)
    readB(b1, pW1, 0, 1);
    BAR(); LGKM0; quad(b1, 1); BAR();
    readA(pX1, 1); readB(b0, pW1, 1, 0);
    BAR(); LGKM0; quad(b0, 0); BAR();
    readB(b1, pW1, 1, 1);
    LGKM0; quad(b1, 1);
  }

  // ---- epilogue: row sums of squares; undo the 64x A-scale (x 2^-12) ------
  // acc[mt][nf] reg r: row = tile_m*256 + (wr4*2+mt)*32 + (r&3) + 8*(r>>2) + 4*hi
  float v[2][16];
#pragma unroll
  for (int mt = 0; mt < 2; ++mt)
#pragma unroll
    for (int r = 0; r < 16; ++r) {
      float s = 0.f;
#pragma unroll
      for (int nf = 0; nf < 4; ++nf) {
        float c = acc[mt][nf][r];
        s += c * c;
      }
      s += __shfl_xor(s, 1, 64);
      s += __shfl_xor(s, 2, 64);
      s += __shfl_xor(s, 4, 64);
      s += __shfl_xor(s, 8, 64);
      s += __shfl_xor(s, 16, 64);
      v[mt][r] = s;
    }

  if ((lane & 31) == 0) {
#pragma unroll
    for (int mt = 0; mt < 2; ++mt)
#pragma unroll
      for (int r = 0; r < 16; ++r)
        rowsum[wc2][(wr4 * 2 + mt) * 32 + (r & 3) + 8 * (r >> 2) + 4 * hi] = v[mt][r];
  }
  __syncthreads();

  if (t < 256) {
    float p = (rowsum[0][t] + rowsum[1][t]) * (1.0f / 4096.0f);
    atomicAdd(&out[tile_m * 256 + t], p);
  }
}

// ---------------- fallback (direct fp32 path, used only if ws too small) ----
__device__ __forceinline__ bf16x8 pack8(const float4& a, const float4& b) {
  bf16x8 r;
  r[0] = (__bf16)a.x; r[1] = (__bf16)a.y; r[2] = (__bf16)a.z; r[3] = (__bf16)a.w;
  r[4] = (__bf16)b.x; r[5] = (__bf16)b.y; r[6] = (__bf16)b.z; r[7] = (__bf16)b.w;
  return r;
}

struct Stage {
  float4 x0a, x0b, x1a, x1b;
  float4 a0a, a0b, a1a, a1b;
};

__global__ __launch_bounds__(256) void gemm_rowsq(const float* __restrict__ X,
                                                  const float* __restrict__ A,
                                                  float* __restrict__ out) {
  __shared__ __align__(16) __bf16 Xs[128 * 32];
  __shared__ __align__(16) __bf16 As[128 * 32];
  __shared__ float rowsum[2][128];

  const int t    = threadIdx.x;
  const int lane = t & 63;
  const int wid  = t >> 6;
  const int wr   = wid >> 1;
  const int wc   = wid & 1;
  const int l15  = lane & 15;
  const int lg   = lane >> 4;

  unsigned bid = blockIdx.x;
  unsigned swz = (bid & 7) * 256u + (bid >> 3);
  const int tile_m = swz >> 5;
  const int tile_n = swz & 31;

  const int srow = t >> 2;
  const int sc   = t & 3;
  const int cw   = sc ^ ((t >> 3) & 3);
  const int woff = srow * 32 + cw * 8;

  const float* gx = X + (size_t)(tile_m * 128 + srow) * DK + sc * 8;
  const float* ga = A + (size_t)(tile_n * 128 + srow) * DK + sc * 8;

  const int chA  = lg ^ ((l15 >> 1) & 3);
  const int aoff = (wr * 64 + l15) * 32 + chA * 8;
  const int boff = (wc * 64 + l15) * 32 + chA * 8;

  f32x4 acc[4][4] = {};

  auto load_tile = [&](int kt) {
    Stage s;
    const float* px = gx + kt * 32;
    const float* pa = ga + kt * 32;
    s.x0a = *(const float4*)(px);
    s.x0b = *(const float4*)(px + 4);
    s.x1a = *(const float4*)(px + (size_t)64 * DK);
    s.x1b = *(const float4*)(px + (size_t)64 * DK + 4);
    s.a0a = *(const float4*)(pa);
    s.a0b = *(const float4*)(pa + 4);
    s.a1a = *(const float4*)(pa + (size_t)64 * DK);
    s.a1b = *(const float4*)(pa + (size_t)64 * DK + 4);
    return s;
  };

  auto store_stage = [&](const Stage& s) {
    *(bf16x8*)(Xs + woff)            = pack8(s.x0a, s.x0b);
    *(bf16x8*)(Xs + woff + 64 * 32)  = pack8(s.x1a, s.x1b);
    *(bf16x8*)(As + woff)            = pack8(s.a0a, s.a0b);
    *(bf16x8*)(As + woff + 64 * 32)  = pack8(s.a1a, s.a1b);
  };

  auto compute = [&]() {
    bf16x8 af[4], bfr[4];
#pragma unroll
    for (int m = 0; m < 4; ++m)
      af[m] = *(const bf16x8*)(Xs + aoff + m * 16 * 32);
#pragma unroll
    for (int n = 0; n < 4; ++n)
      bfr[n] = *(const bf16x8*)(As + boff + n * 16 * 32);
#pragma unroll
    for (int m = 0; m < 4; ++m)
#pragma unroll
      for (int n = 0; n < 4; ++n)
        acc[m][n] = __builtin_amdgcn_mfma_f32_16x16x32_bf16(af[m], bfr[n],
                                                            acc[m][n], 0, 0, 0);
  };

  Stage sa = load_tile(0), sb;

  for (int kt = 0; kt < 128; kt += 2) {
    __syncthreads();
    store_stage(sa);
    sb = load_tile(kt + 1);
    __syncthreads();
    compute();
    __syncthreads();
    store_stage(sb);
    if (kt + 2 < 128) sa = load_tile(kt + 2);
    __syncthreads();
    compute();
  }

  float v[4][4];
#pragma unroll
  for (int m = 0; m < 4; ++m)
#pragma unroll
    for (int j = 0; j < 4; ++j) {
      float s = 0.f;
#pragma unroll
      for (int n = 0; n < 4; ++n) {
        float c = acc[m][n][j];
        s += c * c;
      }
      s += __shfl_xor(s, 1, 64);
      s += __shfl_xor(s, 2, 64);
      s += __shfl_xor(s, 4, 64);
      s += __shfl_xor(s, 8, 64);
      v[m][j] = s;
    }

  if (l15 == 0) {
#pragma unroll
    for (int m = 0; m < 4; ++m)
#pragma unroll
      for (int j = 0; j < 4; ++j)
        rowsum[wc][wr * 64 + m * 16 + lg * 4 + j] = v[m][j];
  }
  __syncthreads();

  if (t < 128) {
    float p = rowsum[0][t] + rowsum[1][t];
    atomicAdd(&out[tile_m * 128 + t], p);
  }
}

extern "C" void kernel_launch(void* const* d_in, const int* in_sizes, int n_in,
                              void* d_out, int out_size, void* d_ws, size_t ws_size,
                              hipStream_t stream) {
  const float* x = (const float*)d_in[0];
  const float* A = (const float*)d_in[1];
  float* out = (float*)d_out;

  hipMemsetAsync(out, 0, (size_t)out_size * sizeof(float), stream);

  if (ws_size >= WS_NEED) {
    unsigned char* wsX = (unsigned char*)d_ws;
    unsigned char* wsW = wsX + X_BYTES;
    hipLaunchKernelGGL(convF8, dim3(2048), dim3(256), 0, stream, x, wsX, XT2, 1.0f);
    hipLaunchKernelGGL(convF8, dim3(2048), dim3(256), 0, stream, A, wsW, WT2, 64.0f);
    hipLaunchKernelGGL(gemm16, dim3(512), dim3(512), 0, stream, wsX, wsW, out);
  } else {
    hipLaunchKernelGGL(gemm_rowsq, dim3(2048), dim3(256), 0, stream, x, A, out);
  }
}

// Round 14
// 162.079 us; speedup vs baseline: 47.2873x; 1.0282x over previous
//
#include <hip/hip_runtime.h>
#include <hip/hip_fp8.h>

typedef __bf16 bf16x8 __attribute__((ext_vector_type(8)));
typedef float  f32x4  __attribute__((ext_vector_type(4)));
typedef float  f32x16 __attribute__((ext_vector_type(16)));
typedef int    i32x4v __attribute__((ext_vector_type(4)));
typedef int    i32x8v __attribute__((ext_vector_type(8)));
typedef unsigned char uchar16v __attribute__((ext_vector_type(16)));

#define NROWS 8192
#define DK    4096
#define MCOLS 4096

// ---- fp8 path geometry: BK=128, tile images byte-identical to bf16 BK=64 ---
#define NKT2   32            // K-tiles of BK=128
#define IMGB   32768         // bytes per 256x128 fp8 tile image (32 KB)
#define REGB   16384         // region bytes (ki half)
#define XT2    32            // 8192/256
#define WT2    16            // 4096/256

#define X_BYTES ((size_t)XT2 * NKT2 * IMGB)   // 33.5 MB
#define W_BYTES ((size_t)WT2 * NKT2 * IMGB)   // 16.8 MB
#define WS_NEED (X_BYTES + W_BYTES)

#define BAR()  do { __builtin_amdgcn_s_barrier(); asm volatile("" ::: "memory"); } while (0)
#define LGKM0  asm volatile("s_waitcnt lgkmcnt(0)" ::: "memory")
#define VM(n)  asm volatile("s_waitcnt vmcnt(" #n ")" ::: "memory")

__device__ __forceinline__ void gload16(const unsigned char* g, unsigned char* l) {
  __builtin_amdgcn_global_load_lds(
      (const __attribute__((address_space(1))) void*)g,
      (__attribute__((address_space(3))) void*)l, 16, 0, 0);
}

// fp32 row-major -> e4m3 fragment image:
// [tile][kt'][ki 0..1][slot 0..7][half 0..1][lane 0..63][16B]
__global__ __launch_bounds__(256) void convF8(const float* __restrict__ src,
                                              unsigned char* __restrict__ dst,
                                              int ntiles, float scale) {
  const int total = ntiles * 65536;
  for (int i = blockIdx.x * blockDim.x + threadIdx.x; i < total;
       i += gridDim.x * blockDim.x) {
    int lane = i & 63;
    int half = (i >> 6) & 1;
    int slot = (i >> 7) & 7;
    int ki   = (i >> 10) & 1;
    int kt   = (i >> 11) & 31;
    int tm   = i >> 16;
    int row = tm * 256 + slot * 32 + (lane & 31);
    int k   = kt * 128 + ki * 64 + (lane >> 5) * 32 + half * 16;
    const float4* p = (const float4*)(src + (size_t)row * DK + k);
    uchar16v o;
#pragma unroll
    for (int q = 0; q < 4; ++q) {
      float4 f = p[q];
      o[q * 4 + 0] = __hip_fp8_e4m3(f.x * scale).__x;
      o[q * 4 + 1] = __hip_fp8_e4m3(f.y * scale).__x;
      o[q * 4 + 2] = __hip_fp8_e4m3(f.z * scale).__x;
      o[q * 4 + 3] = __hip_fp8_e4m3(f.w * scale).__x;
    }
    *(uchar16v*)(dst + (size_t)i * 16) = o;
  }
}

// ---- R13-verified schedule + phase-ahead pipelined LDS reads ---------------
__global__ __launch_bounds__(512, 2) void gemm17(const unsigned char* __restrict__ wsX,
                                                 const unsigned char* __restrict__ wsW,
                                                 float* __restrict__ out) {
  __shared__ __align__(16) unsigned char Xls[2][IMGB];   // 64 KB
  __shared__ __align__(16) unsigned char Wls[2][IMGB];   // 64 KB
  __shared__ float rowsum[2][256];

  const int t    = threadIdx.x;
  const int lane = t & 63;
  const int w    = t >> 6;           // 0..7
  const int wr4  = w >> 1;           // rows wr4*64..+63 (slots 2wr4, 2wr4+1)
  const int wc2  = w & 1;            // cols wc2*128..+127 (slots wc2*4..+3)
  const int hi   = lane >> 5;

  unsigned bid = blockIdx.x;
  unsigned xcd = bid & 7, seq = bid >> 3;
  const int tile_m = (int)((xcd >> 1) * 8 + (seq & 7));    // 0..31
  const int tile_n = (int)((xcd & 1) * 8 + (seq >> 3));    // 0..15

  const unsigned char* xbase = wsX + (size_t)tile_m * ((size_t)NKT2 * IMGB);
  const unsigned char* wbase = wsW + (size_t)tile_n * ((size_t)NKT2 * IMGB);

  const unsigned char* pX0 = &Xls[0][0] + wr4 * 4096 + lane * 16;
  const unsigned char* pX1 = &Xls[1][0] + wr4 * 4096 + lane * 16;
  const unsigned char* pW0 = &Wls[0][0] + wc2 * 8192 + lane * 16;
  const unsigned char* pW1 = &Wls[1][0] + wc2 * 8192 + lane * 16;

  f32x16 acc[2][4] = {};     // [mt][nf] : 128 VGPR
  i32x8v aP[2], aN[2], bP[2], bQ[2], bR[2], bS[2];

  auto ld32 = [&](const unsigned char* p) {
    i32x4v lo = *(const i32x4v*)p;
    i32x4v hh = *(const i32x4v*)(p + 1024);
    i32x8v r;
    r[0] = lo[0]; r[1] = lo[1]; r[2] = lo[2]; r[3] = lo[3];
    r[4] = hh[0]; r[5] = hh[1]; r[6] = hh[2]; r[7] = hh[3];
    return r;
  };

  auto readA = [&](i32x8v (&a)[2], const unsigned char* p, int ki) {
#pragma unroll
    for (int mt = 0; mt < 2; ++mt)
      a[mt] = ld32(p + ki * REGB + mt * 2048);
  };

  auto readB = [&](i32x8v (&b)[2], const unsigned char* p, int ki, int bh) {
#pragma unroll
    for (int nf2 = 0; nf2 < 2; ++nf2)
      b[nf2] = ld32(p + ki * REGB + (bh * 2 + nf2) * 2048);
  };

  auto quad = [&](const i32x8v (&a)[2], const i32x8v (&b)[2], int bh) {
    __builtin_amdgcn_s_setprio(1);
#pragma unroll
    for (int mt = 0; mt < 2; ++mt)
#pragma unroll
      for (int nf2 = 0; nf2 < 2; ++nf2)
        acc[mt][bh * 2 + nf2] = __builtin_amdgcn_mfma_scale_f32_32x32x64_f8f6f4(
            a[mt], b[nf2], acc[mt][bh * 2 + nf2],
            0, 0,                    // cbsz/blgp = FP8 e4m3
            0, 0x7F7F7F7F,           // scale A = 1.0
            0, 0x7F7F7F7F);          // scale B = 1.0
    __builtin_amdgcn_s_setprio(0);
  };

  auto stage = [&](const unsigned char* srcImg, int regionOff, unsigned char* ldsImg) {
    const unsigned char* s0 = srcImg + regionOff + t * 16;
    unsigned char* d0 = ldsImg + regionOff + w * 1024;   // wave-uniform dst
    gload16(s0, d0);
    gload16(s0 + 8192, d0 + 8192);
  };

  // prologue (R13-verified FIFO): VM(8) forces X0(0),W0(0)
  stage(xbase,         0,    &Xls[0][0]);   // X0(0)
  stage(wbase,         0,    &Wls[0][0]);   // W0(0)
  stage(xbase,         REGB, &Xls[0][0]);   // X1(0)
  stage(wbase,         REGB, &Wls[0][0]);   // W1(0)
  stage(xbase + IMGB,  0,    &Xls[1][0]);   // X0(1)
  stage(wbase + IMGB,  0,    &Wls[1][0]);   // W0(1)
  VM(8);
  BAR();

  for (int it = 0; it < 15; ++it) {
    const int h0 = 2 * it;
    const unsigned char* xi1 = xbase + (size_t)(h0 + 1) * IMGB;
    const unsigned char* wi1 = wbase + (size_t)(h0 + 1) * IMGB;
    const unsigned char* xi2 = xbase + (size_t)(h0 + 2) * IMGB;
    const unsigned char* wi2 = wbase + (size_t)(h0 + 2) * IMGB;
    const unsigned char* xi3 = xbase + (size_t)(h0 + 3) * IMGB;
    const unsigned char* wi3 = wbase + (size_t)(h0 + 3) * IMGB;

    // ---- half-iter A: tile h0 in buf0 ----
    // p1: also pre-read bQ (ki0,bh1; region guaranteed at tile entry)
    readA(aP, pX0, 0); readB(bP, pW0, 0, 0); readB(bQ, pW0, 0, 1);
    stage(xi1, REGB, &Xls[1][0]);                 // X1(h0+1)
    BAR(); quad(aP, bP, 0); VM(6); BAR();         // forces X1,W1(h0)
    // p2: pre-read ki1 operands (guaranteed by p1's VM6+BAR)
    readA(aN, pX0, 1); readB(bR, pW0, 1, 0);
    stage(wi1, REGB, &Wls[1][0]);                 // W1(h0+1)
    BAR(); quad(aP, bQ, 1); BAR();
    // p3: pre-read bS
    readB(bS, pW0, 1, 1);
    stage(xi2, 0, &Xls[0][0]);                    // X0(h0+2)
    BAR(); quad(aN, bR, 0); BAR();
    // p4
    stage(wi2, 0, &Wls[0][0]);                    // W0(h0+2)
    BAR(); quad(aN, bS, 1); VM(8); BAR();         // forces X0,W0(h0+1)

    // ---- half-iter B: tile h0+1 in buf1 ----
    readA(aP, pX1, 0); readB(bP, pW1, 0, 0); readB(bQ, pW1, 0, 1);
    stage(xi2, REGB, &Xls[0][0]);                 // X1(h0+2)
    BAR(); quad(aP, bP, 0); VM(6); BAR();         // forces X1,W1(h0+1)
    readA(aN, pX1, 1); readB(bR, pW1, 1, 0);
    stage(wi2, REGB, &Wls[0][0]);                 // W1(h0+2)
    BAR(); quad(aP, bQ, 1); BAR();
    readB(bS, pW1, 1, 1);
    stage(xi3, 0, &Xls[1][0]);                    // X0(h0+3)
    BAR(); quad(aN, bR, 0); BAR();
    stage(wi3, 0, &Wls[1][0]);                    // W0(h0+3)
    BAR(); quad(aN, bS, 1); VM(8); BAR();         // forces X0,W0(h0+2)
  }

  // ---- peeled tail: tiles 30 (buf0), 31 (buf1) — R13 tail, renamed regs ----
  {
    const unsigned char* xi1 = xbase + (size_t)31 * IMGB;
    const unsigned char* wi1 = wbase + (size_t)31 * IMGB;

    readA(aP, pX0, 0); readB(bP, pW0, 0, 0);
    stage(xi1, REGB, &Xls[1][0]);                 // X1(31)
    BAR(); LGKM0; quad(aP, bP, 0); VM(6); BAR();  // forces X1,W1(30)
    readB(bQ, pW0, 0, 1);
    stage(wi1, REGB, &Wls[1][0]);                 // W1(31)
    BAR(); LGKM0; quad(aP, bQ, 1); BAR();
    readA(aN, pX0, 1); readB(bR, pW0, 1, 0);
    BAR(); LGKM0; quad(aN, bR, 0); BAR();
    readB(bS, pW0, 1, 1);
    BAR(); LGKM0; quad(aN, bS, 1); VM(4); BAR();  // forces X0,W0(31)
    readA(aP, pX1, 0); readB(bP, pW1, 0, 0);
    BAR(); LGKM0; quad(aP, bP, 0); VM(0); BAR();  // forces X1,W1(31)
    readB(bQ, pW1, 0, 1);
    BAR(); LGKM0; quad(aP, bQ, 1); BAR();
    readA(aN, pX1, 1); readB(bR, pW1, 1, 0);
    BAR(); LGKM0; quad(aN, bR, 0); BAR();
    readB(bS, pW1, 1, 1);
    LGKM0; quad(aN, bS, 1);
  }

  // ---- epilogue: row sums of squares; undo 64x A-scale (x 2^-12) -----------
  float v[2][16];
#pragma unroll
  for (int mt = 0; mt < 2; ++mt)
#pragma unroll
    for (int r = 0; r < 16; ++r) {
      float s = 0.f;
#pragma unroll
      for (int nf = 0; nf < 4; ++nf) {
        float c = acc[mt][nf][r];
        s += c * c;
      }
      s += __shfl_xor(s, 1, 64);
      s += __shfl_xor(s, 2, 64);
      s += __shfl_xor(s, 4, 64);
      s += __shfl_xor(s, 8, 64);
      s += __shfl_xor(s, 16, 64);
      v[mt][r] = s;
    }

  if ((lane & 31) == 0) {
#pragma unroll
    for (int mt = 0; mt < 2; ++mt)
#pragma unroll
      for (int r = 0; r < 16; ++r)
        rowsum[wc2][(wr4 * 2 + mt) * 32 + (r & 3) + 8 * (r >> 2) + 4 * hi] = v[mt][r];
  }
  __syncthreads();

  if (t < 256) {
    float p = (rowsum[0][t] + rowsum[1][t]) * (1.0f / 4096.0f);
    atomicAdd(&out[tile_m * 256 + t], p);
  }
}

// ---------------- fallback (direct fp32 path, used only if ws too small) ----
__device__ __forceinline__ bf16x8 pack8(const float4& a, const float4& b) {
  bf16x8 r;
  r[0] = (__bf16)a.x; r[1] = (__bf16)a.y; r[2] = (__bf16)a.z; r[3] = (__bf16)a.w;
  r[4] = (__bf16)b.x; r[5] = (__bf16)b.y; r[6] = (__bf16)b.z; r[7] = (__bf16)b.w;
  return r;
}

struct Stage {
  float4 x0a, x0b, x1a, x1b;
  float4 a0a, a0b, a1a, a1b;
};

__global__ __launch_bounds__(256) void gemm_rowsq(const float* __restrict__ X,
                                                  const float* __restrict__ A,
                                                  float* __restrict__ out) {
  __shared__ __align__(16) __bf16 Xs[128 * 32];
  __shared__ __align__(16) __bf16 As[128 * 32];
  __shared__ float rowsum[2][128];

  const int t    = threadIdx.x;
  const int lane = t & 63;
  const int wid  = t >> 6;
  const int wr   = wid >> 1;
  const int wc   = wid & 1;
  const int l15  = lane & 15;
  const int lg   = lane >> 4;

  unsigned bid = blockIdx.x;
  unsigned swz = (bid & 7) * 256u + (bid >> 3);
  const int tile_m = swz >> 5;
  const int tile_n = swz & 31;

  const int srow = t >> 2;
  const int sc   = t & 3;
  const int cw   = sc ^ ((t >> 3) & 3);
  const int woff = srow * 32 + cw * 8;

  const float* gx = X + (size_t)(tile_m * 128 + srow) * DK + sc * 8;
  const float* ga = A + (size_t)(tile_n * 128 + srow) * DK + sc * 8;

  const int chA  = lg ^ ((l15 >> 1) & 3);
  const int aoff = (wr * 64 + l15) * 32 + chA * 8;
  const int boff = (wc * 64 + l15) * 32 + chA * 8;

  f32x4 acc[4][4] = {};

  auto load_tile = [&](int kt) {
    Stage s;
    const float* px = gx + kt * 32;
    const float* pa = ga + kt * 32;
    s.x0a = *(const float4*)(px);
    s.x0b = *(const float4*)(px + 4);
    s.x1a = *(const float4*)(px + (size_t)64 * DK);
    s.x1b = *(const float4*)(px + (size_t)64 * DK + 4);
    s.a0a = *(const float4*)(pa);
    s.a0b = *(const float4*)(pa + 4);
    s.a1a = *(const float4*)(pa + (size_t)64 * DK);
    s.a1b = *(const float4*)(pa + (size_t)64 * DK + 4);
    return s;
  };

  auto store_stage = [&](const Stage& s) {
    *(bf16x8*)(Xs + woff)            = pack8(s.x0a, s.x0b);
    *(bf16x8*)(Xs + woff + 64 * 32)  = pack8(s.x1a, s.x1b);
    *(bf16x8*)(As + woff)            = pack8(s.a0a, s.a0b);
    *(bf16x8*)(As + woff + 64 * 32)  = pack8(s.a1a, s.a1b);
  };

  auto compute = [&]() {
    bf16x8 af[4], bfr[4];
#pragma unroll
    for (int m = 0; m < 4; ++m)
      af[m] = *(const bf16x8*)(Xs + aoff + m * 16 * 32);
#pragma unroll
    for (int n = 0; n < 4; ++n)
      bfr[n] = *(const bf16x8*)(As + boff + n * 16 * 32);
#pragma unroll
    for (int m = 0; m < 4; ++m)
#pragma unroll
      for (int n = 0; n < 4; ++n)
        acc[m][n] = __builtin_amdgcn_mfma_f32_16x16x32_bf16(af[m], bfr[n],
                                                            acc[m][n], 0, 0, 0);
  };

  Stage sa = load_tile(0), sb;

  for (int kt = 0; kt < 128; kt += 2) {
    __syncthreads();
    store_stage(sa);
    sb = load_tile(kt + 1);
    __syncthreads();
    compute();
    __syncthreads();
    store_stage(sb);
    if (kt + 2 < 128) sa = load_tile(kt + 2);
    __syncthreads();
    compute();
  }

  float v[4][4];
#pragma unroll
  for (int m = 0; m < 4; ++m)
#pragma unroll
    for (int j = 0; j < 4; ++j) {
      float s = 0.f;
#pragma unroll
      for (int n = 0; n < 4; ++n) {
        float c = acc[m][n][j];
        s += c * c;
      }
      s += __shfl_xor(s, 1, 64);
      s += __shfl_xor(s, 2, 64);
      s += __shfl_xor(s, 4, 64);
      s += __shfl_xor(s, 8, 64);
      v[m][j] = s;
    }

  if (l15 == 0) {
#pragma unroll
    for (int m = 0; m < 4; ++m)
#pragma unroll
      for (int j = 0; j < 4; ++j)
        rowsum[wc][wr * 64 + m * 16 + lg * 4 + j] = v[m][j];
  }
  __syncthreads();

  if (t < 128) {
    float p = rowsum[0][t] + rowsum[1][t];
    atomicAdd(&out[tile_m * 128 + t], p);
  }
}

extern "C" void kernel_launch(void* const* d_in, const int* in_sizes, int n_in,
                              void* d_out, int out_size, void* d_ws, size_t ws_size,
                              hipStream_t stream) {
  const float* x = (const float*)d_in[0];
  const float* A = (const float*)d_in[1];
  float* out = (float*)d_out;

  hipMemsetAsync(out, 0, (size_t)out_size * sizeof(float), stream);

  if (ws_size >= WS_NEED) {
    unsigned char* wsX = (unsigned char*)d_ws;
    unsigned char* wsW = wsX + X_BYTES;
    hipLaunchKernelGGL(convF8, dim3(2048), dim3(256), 0, stream, x, wsX, XT2, 1.0f);
    hipLaunchKernelGGL(convF8, dim3(2048), dim3(256), 0, stream, A, wsW, WT2, 64.0f);
    hipLaunchKernelGGL(gemm17, dim3(512), dim3(512), 0, stream, wsX, wsW, out);
  } else {
    hipLaunchKernelGGL(gemm_rowsq, dim3(2048), dim3(256), 0, stream, x, A, out);
  }
}

// Round 15
// 158.992 us; speedup vs baseline: 48.2055x; 1.0194x over previous
//
#include <hip/hip_runtime.h>
#include <hip/hip_fp8.h>

typedef __bf16 bf16x8 __attribute__((ext_vector_type(8)));
typedef float  f32x4  __attribute__((ext_vector_type(4)));
typedef float  f32x16 __attribute__((ext_vector_type(16)));
typedef int    i32x4v __attribute__((ext_vector_type(4)));
typedef int    i32x8v __attribute__((ext_vector_type(8)));
typedef unsigned char uchar16v __attribute__((ext_vector_type(16)));

#define NROWS 8192
#define DK    4096
#define MCOLS 4096

// ---- fp8 path geometry: BK=128 ---------------------------------------------
#define NKT2   32            // K-tiles of BK=128
#define IMGB   32768         // bytes per 256x128 fp8 tile image (32 KB)
#define REGB   16384         // region bytes (ki half)
#define XT2    32            // 8192/256
#define WT2    16            // 4096/256

#define X_BYTES ((size_t)XT2 * NKT2 * IMGB)   // 33.5 MB
#define W_BYTES ((size_t)WT2 * NKT2 * IMGB)   // 16.8 MB
#define WS_NEED (X_BYTES + W_BYTES)

#define BAR()  do { __builtin_amdgcn_s_barrier(); asm volatile("" ::: "memory"); } while (0)
#define LGKM0  asm volatile("s_waitcnt lgkmcnt(0)" ::: "memory")
#define VM(n)  asm volatile("s_waitcnt vmcnt(" #n ")" ::: "memory")

__device__ __forceinline__ void gload16(const unsigned char* g, unsigned char* l) {
  __builtin_amdgcn_global_load_lds(
      (const __attribute__((address_space(1))) void*)g,
      (__attribute__((address_space(3))) void*)l, 16, 0, 0);
}

// fp32 row-major -> e4m3 fragment image:
// [tile][kt'][ki 0..1][slot 0..7][half 0..1][lane 0..63][16B]
__global__ __launch_bounds__(256) void convF8(const float* __restrict__ src,
                                              unsigned char* __restrict__ dst,
                                              int ntiles, float scale) {
  const int total = ntiles * 65536;
  for (int i = blockIdx.x * blockDim.x + threadIdx.x; i < total;
       i += gridDim.x * blockDim.x) {
    int lane = i & 63;
    int half = (i >> 6) & 1;
    int slot = (i >> 7) & 7;
    int ki   = (i >> 10) & 1;
    int kt   = (i >> 11) & 31;
    int tm   = i >> 16;
    int row = tm * 256 + slot * 32 + (lane & 31);
    int k   = kt * 128 + ki * 64 + (lane >> 5) * 32 + half * 16;
    const float4* p = (const float4*)(src + (size_t)row * DK + k);
    uchar16v o;
#pragma unroll
    for (int q = 0; q < 4; ++q) {
      float4 f = p[q];
      o[q * 4 + 0] = __hip_fp8_e4m3(f.x * scale).__x;
      o[q * 4 + 1] = __hip_fp8_e4m3(f.y * scale).__x;
      o[q * 4 + 2] = __hip_fp8_e4m3(f.z * scale).__x;
      o[q * 4 + 3] = __hip_fp8_e4m3(f.w * scale).__x;
    }
    *(uchar16v*)(dst + (size_t)i * 16) = o;
  }
}

// ---- R14 kernel with single barrier per phase (4 barriers/K-tile) ----------
__global__ __launch_bounds__(512, 2) void gemm18(const unsigned char* __restrict__ wsX,
                                                 const unsigned char* __restrict__ wsW,
                                                 float* __restrict__ out) {
  __shared__ __align__(16) unsigned char Xls[2][IMGB];   // 64 KB
  __shared__ __align__(16) unsigned char Wls[2][IMGB];   // 64 KB
  __shared__ float rowsum[2][256];

  const int t    = threadIdx.x;
  const int lane = t & 63;
  const int w    = t >> 6;           // 0..7
  const int wr4  = w >> 1;           // rows wr4*64..+63 (slots 2wr4, 2wr4+1)
  const int wc2  = w & 1;            // cols wc2*128..+127 (slots wc2*4..+3)
  const int hi   = lane >> 5;

  unsigned bid = blockIdx.x;
  unsigned xcd = bid & 7, seq = bid >> 3;
  const int tile_m = (int)((xcd >> 1) * 8 + (seq & 7));    // 0..31
  const int tile_n = (int)((xcd & 1) * 8 + (seq >> 3));    // 0..15

  const unsigned char* xbase = wsX + (size_t)tile_m * ((size_t)NKT2 * IMGB);
  const unsigned char* wbase = wsW + (size_t)tile_n * ((size_t)NKT2 * IMGB);

  const unsigned char* pX0 = &Xls[0][0] + wr4 * 4096 + lane * 16;
  const unsigned char* pX1 = &Xls[1][0] + wr4 * 4096 + lane * 16;
  const unsigned char* pW0 = &Wls[0][0] + wc2 * 8192 + lane * 16;
  const unsigned char* pW1 = &Wls[1][0] + wc2 * 8192 + lane * 16;

  f32x16 acc[2][4] = {};     // [mt][nf] : 128 VGPR
  i32x8v aP[2], aN[2], bP[2], bQ[2], bR[2], bS[2];

  auto ld32 = [&](const unsigned char* p) {
    i32x4v lo = *(const i32x4v*)p;
    i32x4v hh = *(const i32x4v*)(p + 1024);
    i32x8v r;
    r[0] = lo[0]; r[1] = lo[1]; r[2] = lo[2]; r[3] = lo[3];
    r[4] = hh[0]; r[5] = hh[1]; r[6] = hh[2]; r[7] = hh[3];
    return r;
  };

  auto readA = [&](i32x8v (&a)[2], const unsigned char* p, int ki) {
#pragma unroll
    for (int mt = 0; mt < 2; ++mt)
      a[mt] = ld32(p + ki * REGB + mt * 2048);
  };

  auto readB = [&](i32x8v (&b)[2], const unsigned char* p, int ki, int bh) {
#pragma unroll
    for (int nf2 = 0; nf2 < 2; ++nf2)
      b[nf2] = ld32(p + ki * REGB + (bh * 2 + nf2) * 2048);
  };

  auto quad = [&](const i32x8v (&a)[2], const i32x8v (&b)[2], int bh) {
    __builtin_amdgcn_s_setprio(1);
#pragma unroll
    for (int mt = 0; mt < 2; ++mt)
#pragma unroll
      for (int nf2 = 0; nf2 < 2; ++nf2)
        acc[mt][bh * 2 + nf2] = __builtin_amdgcn_mfma_scale_f32_32x32x64_f8f6f4(
            a[mt], b[nf2], acc[mt][bh * 2 + nf2],
            0, 0,                    // cbsz/blgp = FP8 e4m3
            0, 0x7F7F7F7F,           // scale A = 1.0
            0, 0x7F7F7F7F);          // scale B = 1.0
    __builtin_amdgcn_s_setprio(0);
  };

  auto stage = [&](const unsigned char* srcImg, int regionOff, unsigned char* ldsImg) {
    const unsigned char* s0 = srcImg + regionOff + t * 16;
    unsigned char* d0 = ldsImg + regionOff + w * 1024;   // wave-uniform dst
    gload16(s0, d0);
    gload16(s0 + 8192, d0 + 8192);
  };

  // prologue (R13-verified FIFO): VM(8) forces X0(0),W0(0)
  stage(xbase,         0,    &Xls[0][0]);   // X0(0)
  stage(wbase,         0,    &Wls[0][0]);   // W0(0)
  stage(xbase,         REGB, &Xls[0][0]);   // X1(0)
  stage(wbase,         REGB, &Wls[0][0]);   // W1(0)
  stage(xbase + IMGB,  0,    &Xls[1][0]);   // X0(1)
  stage(wbase + IMGB,  0,    &Wls[1][0]);   // W0(1)
  VM(8);
  BAR();

  for (int it = 0; it < 15; ++it) {
    const int h0 = 2 * it;
    const unsigned char* xi1 = xbase + (size_t)(h0 + 1) * IMGB;
    const unsigned char* wi1 = wbase + (size_t)(h0 + 1) * IMGB;
    const unsigned char* xi2 = xbase + (size_t)(h0 + 2) * IMGB;
    const unsigned char* wi2 = wbase + (size_t)(h0 + 2) * IMGB;
    const unsigned char* xi3 = xbase + (size_t)(h0 + 3) * IMGB;
    const unsigned char* wi3 = wbase + (size_t)(h0 + 3) * IMGB;

    // ---- half-iter A: tile h0 in buf0 (one barrier per phase) ----
    // p1
    readA(aP, pX0, 0); readB(bP, pW0, 0, 0); readB(bQ, pW0, 0, 1);
    stage(xi1, REGB, &Xls[1][0]);                 // X1(h0+1)
    quad(aP, bP, 0); VM(6); BAR();                // forces X1,W1(h0)
    // p2
    readA(aN, pX0, 1); readB(bR, pW0, 1, 0);
    stage(wi1, REGB, &Wls[1][0]);                 // W1(h0+1)
    quad(aP, bQ, 1); BAR();
    // p3
    readB(bS, pW0, 1, 1);
    stage(xi2, 0, &Xls[0][0]);                    // X0(h0+2)
    quad(aN, bR, 0); BAR();
    // p4
    stage(wi2, 0, &Wls[0][0]);                    // W0(h0+2)
    quad(aN, bS, 1); VM(8); BAR();                // forces X0,W0(h0+1)

    // ---- half-iter B: tile h0+1 in buf1 ----
    readA(aP, pX1, 0); readB(bP, pW1, 0, 0); readB(bQ, pW1, 0, 1);
    stage(xi2, REGB, &Xls[0][0]);                 // X1(h0+2)
    quad(aP, bP, 0); VM(6); BAR();                // forces X1,W1(h0+1)
    readA(aN, pX1, 1); readB(bR, pW1, 1, 0);
    stage(wi2, REGB, &Wls[0][0]);                 // W1(h0+2)
    quad(aP, bQ, 1); BAR();
    readB(bS, pW1, 1, 1);
    stage(xi3, 0, &Xls[1][0]);                    // X0(h0+3)
    quad(aN, bR, 0); BAR();
    stage(wi3, 0, &Wls[1][0]);                    // W0(h0+3)
    quad(aN, bS, 1); VM(8); BAR();                // forces X0,W0(h0+2)
  }

  // ---- peeled tail: tiles 30 (buf0), 31 (buf1) — R13-verified form ---------
  {
    const unsigned char* xi1 = xbase + (size_t)31 * IMGB;
    const unsigned char* wi1 = wbase + (size_t)31 * IMGB;

    readA(aP, pX0, 0); readB(bP, pW0, 0, 0);
    stage(xi1, REGB, &Xls[1][0]);                 // X1(31)
    BAR(); LGKM0; quad(aP, bP, 0); VM(6); BAR();  // forces X1,W1(30)
    readB(bQ, pW0, 0, 1);
    stage(wi1, REGB, &Wls[1][0]);                 // W1(31)
    BAR(); LGKM0; quad(aP, bQ, 1); BAR();
    readA(aN, pX0, 1); readB(bR, pW0, 1, 0);
    BAR(); LGKM0; quad(aN, bR, 0); BAR();
    readB(bS, pW0, 1, 1);
    BAR(); LGKM0; quad(aN, bS, 1); VM(4); BAR();  // forces X0,W0(31)
    readA(aP, pX1, 0); readB(bP, pW1, 0, 0);
    BAR(); LGKM0; quad(aP, bP, 0); VM(0); BAR();  // forces X1,W1(31)
    readB(bQ, pW1, 0, 1);
    BAR(); LGKM0; quad(aP, bQ, 1); BAR();
    readA(aN, pX1, 1); readB(bR, pW1, 1, 0);
    BAR(); LGKM0; quad(aN, bR, 0); BAR();
    readB(bS, pW1, 1, 1);
    LGKM0; quad(aN, bS, 1);
  }

  // ---- epilogue: row sums of squares; undo 64x A-scale (x 2^-12) -----------
  float v[2][16];
#pragma unroll
  for (int mt = 0; mt < 2; ++mt)
#pragma unroll
    for (int r = 0; r < 16; ++r) {
      float s = 0.f;
#pragma unroll
      for (int nf = 0; nf < 4; ++nf) {
        float c = acc[mt][nf][r];
        s += c * c;
      }
      s += __shfl_xor(s, 1, 64);
      s += __shfl_xor(s, 2, 64);
      s += __shfl_xor(s, 4, 64);
      s += __shfl_xor(s, 8, 64);
      s += __shfl_xor(s, 16, 64);
      v[mt][r] = s;
    }

  if ((lane & 31) == 0) {
#pragma unroll
    for (int mt = 0; mt < 2; ++mt)
#pragma unroll
      for (int r = 0; r < 16; ++r)
        rowsum[wc2][(wr4 * 2 + mt) * 32 + (r & 3) + 8 * (r >> 2) + 4 * hi] = v[mt][r];
  }
  __syncthreads();

  if (t < 256) {
    float p = (rowsum[0][t] + rowsum[1][t]) * (1.0f / 4096.0f);
    atomicAdd(&out[tile_m * 256 + t], p);
  }
}

// ---------------- fallback (direct fp32 path, used only if ws too small) ----
__device__ __forceinline__ bf16x8 pack8(const float4& a, const float4& b) {
  bf16x8 r;
  r[0] = (__bf16)a.x; r[1] = (__bf16)a.y; r[2] = (__bf16)a.z; r[3] = (__bf16)a.w;
  r[4] = (__bf16)b.x; r[5] = (__bf16)b.y; r[6] = (__bf16)b.z; r[7] = (__bf16)b.w;
  return r;
}

struct Stage {
  float4 x0a, x0b, x1a, x1b;
  float4 a0a, a0b, a1a, a1b;
};

__global__ __launch_bounds__(256) void gemm_rowsq(const float* __restrict__ X,
                                                  const float* __restrict__ A,
                                                  float* __restrict__ out) {
  __shared__ __align__(16) __bf16 Xs[128 * 32];
  __shared__ __align__(16) __bf16 As[128 * 32];
  __shared__ float rowsum[2][128];

  const int t    = threadIdx.x;
  const int lane = t & 63;
  const int wid  = t >> 6;
  const int wr   = wid >> 1;
  const int wc   = wid & 1;
  const int l15  = lane & 15;
  const int lg   = lane >> 4;

  unsigned bid = blockIdx.x;
  unsigned swz = (bid & 7) * 256u + (bid >> 3);
  const int tile_m = swz >> 5;
  const int tile_n = swz & 31;

  const int srow = t >> 2;
  const int sc   = t & 3;
  const int cw   = sc ^ ((t >> 3) & 3);
  const int woff = srow * 32 + cw * 8;

  const float* gx = X + (size_t)(tile_m * 128 + srow) * DK + sc * 8;
  const float* ga = A + (size_t)(tile_n * 128 + srow) * DK + sc * 8;

  const int chA  = lg ^ ((l15 >> 1) & 3);
  const int aoff = (wr * 64 + l15) * 32 + chA * 8;
  const int boff = (wc * 64 + l15) * 32 + chA * 8;

  f32x4 acc[4][4] = {};

  auto load_tile = [&](int kt) {
    Stage s;
    const float* px = gx + kt * 32;
    const float* pa = ga + kt * 32;
    s.x0a = *(const float4*)(px);
    s.x0b = *(const float4*)(px + 4);
    s.x1a = *(const float4*)(px + (size_t)64 * DK);
    s.x1b = *(const float4*)(px + (size_t)64 * DK + 4);
    s.a0a = *(const float4*)(pa);
    s.a0b = *(const float4*)(pa + 4);
    s.a1a = *(const float4*)(pa + (size_t)64 * DK);
    s.a1b = *(const float4*)(pa + (size_t)64 * DK + 4);
    return s;
  };

  auto store_stage = [&](const Stage& s) {
    *(bf16x8*)(Xs + woff)            = pack8(s.x0a, s.x0b);
    *(bf16x8*)(Xs + woff + 64 * 32)  = pack8(s.x1a, s.x1b);
    *(bf16x8*)(As + woff)            = pack8(s.a0a, s.a0b);
    *(bf16x8*)(As + woff + 64 * 32)  = pack8(s.a1a, s.a1b);
  };

  auto compute = [&]() {
    bf16x8 af[4], bfr[4];
#pragma unroll
    for (int m = 0; m < 4; ++m)
      af[m] = *(const bf16x8*)(Xs + aoff + m * 16 * 32);
#pragma unroll
    for (int n = 0; n < 4; ++n)
      bfr[n] = *(const bf16x8*)(As + boff + n * 16 * 32);
#pragma unroll
    for (int m = 0; m < 4; ++m)
#pragma unroll
      for (int n = 0; n < 4; ++n)
        acc[m][n] = __builtin_amdgcn_mfma_f32_16x16x32_bf16(af[m], bfr[n],
                                                            acc[m][n], 0, 0, 0);
  };

  Stage sa = load_tile(0), sb;

  for (int kt = 0; kt < 128; kt += 2) {
    __syncthreads();
    store_stage(sa);
    sb = load_tile(kt + 1);
    __syncthreads();
    compute();
    __syncthreads();
    store_stage(sb);
    if (kt + 2 < 128) sa = load_tile(kt + 2);
    __syncthreads();
    compute();
  }

  float v[4][4];
#pragma unroll
  for (int m = 0; m < 4; ++m)
#pragma unroll
    for (int j = 0; j < 4; ++j) {
      float s = 0.f;
#pragma unroll
      for (int n = 0; n < 4; ++n) {
        float c = acc[m][n][j];
        s += c * c;
      }
      s += __shfl_xor(s, 1, 64);
      s += __shfl_xor(s, 2, 64);
      s += __shfl_xor(s, 4, 64);
      s += __shfl_xor(s, 8, 64);
      v[m][j] = s;
    }

  if (l15 == 0) {
#pragma unroll
    for (int m = 0; m < 4; ++m)
#pragma unroll
      for (int j = 0; j < 4; ++j)
        rowsum[wc][wr * 64 + m * 16 + lg * 4 + j] = v[m][j];
  }
  __syncthreads();

  if (t < 128) {
    float p = rowsum[0][t] + rowsum[1][t];
    atomicAdd(&out[tile_m * 128 + t], p);
  }
}

extern "C" void kernel_launch(void* const* d_in, const int* in_sizes, int n_in,
                              void* d_out, int out_size, void* d_ws, size_t ws_size,
                              hipStream_t stream) {
  const float* x = (const float*)d_in[0];
  const float* A = (const float*)d_in[1];
  float* out = (float*)d_out;

  hipMemsetAsync(out, 0, (size_t)out_size * sizeof(float), stream);

  if (ws_size >= WS_NEED) {
    unsigned char* wsX = (unsigned char*)d_ws;
    unsigned char* wsW = wsX + X_BYTES;
    hipLaunchKernelGGL(convF8, dim3(2048), dim3(256), 0, stream, x, wsX, XT2, 1.0f);
    hipLaunchKernelGGL(convF8, dim3(2048), dim3(256), 0, stream, A, wsW, WT2, 64.0f);
    hipLaunchKernelGGL(gemm18, dim3(512), dim3(512), 0, stream, wsX, wsW, out);
  } else {
    hipLaunchKernelGGL(gemm_rowsq, dim3(2048), dim3(256), 0, stream, x, A, out);
  }
}